// Round 4
// baseline (54508.691 us; speedup 1.0000x reference)
//
#include <hip/hip_runtime.h>
#include <hip/hip_bf16.h>
#include <math.h>

#define TPB 256
typedef unsigned short u16;

__device__ __forceinline__ float b2f(u16 u){ return __uint_as_float(((unsigned)u)<<16); }
__device__ __forceinline__ u16 f2b(float f){
  unsigned x = __float_as_uint(f);
  unsigned r = (x + 0x7fffu + ((x>>16)&1u)) >> 16;
  return (u16)r;
}

// ---------------- Conv1 (per 32-batch chunk): [32,3,40,72] -> relu conv3x3 pad1 -> [32,64,40,72]
__global__ __launch_bounds__(TPB) void conv1_kernel(const float* __restrict__ x,
    const float* __restrict__ w, float* __restrict__ out){
  int gid = blockIdx.x*TPB + threadIdx.x;
  int ox = gid % 72; int t1 = gid/72; int oy = t1 % 40; t1 /= 40;
  int oc = t1 & 63; int b = t1 >> 6;
  float wv[27];
  #pragma unroll
  for (int i=0;i<27;i++) wv[i] = w[oc*27+i];
  const float* xb = x + (size_t)b*3*40*72;
  float acc = 0.f;
  #pragma unroll
  for (int dy=0; dy<3; dy++){
    int iy = oy-1+dy; if ((unsigned)iy >= 40u) continue;
    #pragma unroll
    for (int dx=0; dx<3; dx++){
      int ix = ox-1+dx; if ((unsigned)ix >= 72u) continue;
      #pragma unroll
      for (int ic=0; ic<3; ic++)
        acc += xb[(ic*40+iy)*72+ix] * wv[(ic*3+dy)*3+dx];
    }
  }
  out[gid] = fmaxf(acc, 0.f);
}

// ---------------- MaxPool 3x3 s2 p1
__global__ __launch_bounds__(TPB) void maxpool_kernel(const float* __restrict__ in,
    float* __restrict__ out, int H, int W, int OH, int OW, int total){
  int gid = blockIdx.x*TPB + threadIdx.x;
  if (gid >= total) return;
  int ox = gid % OW; int t1 = gid / OW; int oy = t1 % OH; int bc = t1 / OH;
  const float* ip = in + (size_t)bc*H*W;
  float m = -INFINITY;
  #pragma unroll
  for (int dy=0; dy<3; dy++){
    int iy = oy*2-1+dy; if ((unsigned)iy >= (unsigned)H) continue;
    #pragma unroll
    for (int dx=0; dx<3; dx++){
      int ix = ox*2-1+dx; if ((unsigned)ix >= (unsigned)W) continue;
      m = fmaxf(m, ip[iy*W+ix]);
    }
  }
  out[gid] = m;
}

// ---------------- Conv2 (per chunk): [32,64,20,36] -> relu conv3x3 pad1 -> [32,64,20,36]
__global__ __launch_bounds__(TPB) void conv2_kernel(const float* __restrict__ in,
    const float* __restrict__ w, float* __restrict__ out){
  __shared__ float ws[576];
  int blk = blockIdx.x;
  int sub = blk % 3; int ocb = blk / 3; int oc = ocb & 63; int b = ocb >> 6;
  for (int i = threadIdx.x; i < 576; i += TPB) ws[i] = w[oc*576 + i];
  __syncthreads();
  if (threadIdx.x >= 240) return;
  int pos = sub*240 + threadIdx.x;
  int oy = pos/36, ox = pos%36;
  const float* ib = in + (size_t)b*64*720;
  float acc = 0.f;
  for (int ic=0; ic<64; ic++){
    const float* ip = ib + ic*720;
    const float* wp = ws + ic*9;
    #pragma unroll
    for (int dy=0; dy<3; dy++){
      int iy = oy-1+dy; if ((unsigned)iy >= 20u) continue;
      #pragma unroll
      for (int dx=0; dx<3; dx++){
        int ix = ox-1+dx; if ((unsigned)ix >= 36u) continue;
        acc += ip[iy*36+ix]*wp[dy*3+dx];
      }
    }
  }
  out[(size_t)(b*64+oc)*720 + pos] = fmaxf(acc, 0.f);
}

// ---------------- transpose + pos_emb (per chunk): [32,64,10,18] -> t [32,180,64]
__global__ __launch_bounds__(TPB) void posadd_kernel(const float* __restrict__ p2,
    const float* __restrict__ pos, float* __restrict__ t){
  int gid = blockIdx.x*TPB + threadIdx.x;     // total 368,640
  int d = gid & 63; int n = (gid >> 6) % 180; int b = gid / (180*64);
  t[gid] = p2[(size_t)(b*64+d)*180 + n] + pos[n*64+d];
}

// ---------------- LayerNorm over last dim 64: one wave per row
__global__ __launch_bounds__(TPB) void ln_kernel(const float* __restrict__ x,
    const float* __restrict__ g, const float* __restrict__ bta, float* __restrict__ out){
  int row = blockIdx.x*4 + (threadIdx.x>>6);
  int lane = threadIdx.x & 63;
  float v = x[(size_t)row*64 + lane];
  float s = v;
  #pragma unroll
  for (int off=32; off; off>>=1) s += __shfl_xor(s, off);
  float mean = s * (1.f/64.f);
  float d = v - mean;
  float q = d*d;
  #pragma unroll
  for (int off=32; off; off>>=1) q += __shfl_xor(q, off);
  float r = rsqrtf(q*(1.f/64.f) + 1e-5f);
  out[(size_t)row*64 + lane] = d*r*g[lane] + bta[lane];
}

// ---------------- GEMM: C[M,N] = A[M,K] @ B[K,N] (+bias)(+resid)(ACT: 0=none,1=gelu)
template<int ACT, bool RES>
__global__ __launch_bounds__(TPB) void gemm_kernel(const float* __restrict__ A,
    const float* __restrict__ Bw, const float* __restrict__ bias,
    const float* __restrict__ resid, float* __restrict__ Cout, int M, int N, int K){
  __shared__ float As[16][68];
  __shared__ float Bs[16][68];
  int tid = threadIdx.x;
  int tx = tid & 15, ty = tid >> 4;
  int row0 = blockIdx.y*64, col0 = blockIdx.x*64;
  int ar = tid >> 2, ak = (tid & 3) << 2;
  int bk = tid >> 4, bc = (tid & 15) << 2;
  const float* Ap = A + (size_t)(row0+ar)*K + ak;
  const float* Bp = Bw + (size_t)bk*N + col0 + bc;
  float acc[4][4];
  #pragma unroll
  for (int i=0;i<4;i++){ acc[i][0]=0.f; acc[i][1]=0.f; acc[i][2]=0.f; acc[i][3]=0.f; }
  for (int k0=0; k0<K; k0+=16){
    float4 av = *(const float4*)(Ap + k0);
    float4 bv = *(const float4*)(Bp + (size_t)k0*N);
    As[ak+0][ar]=av.x; As[ak+1][ar]=av.y; As[ak+2][ar]=av.z; As[ak+3][ar]=av.w;
    *(float4*)&Bs[bk][bc] = bv;
    __syncthreads();
    #pragma unroll
    for (int k=0;k<16;k++){
      float4 a4 = *(const float4*)&As[k][ty<<2];
      float4 b4 = *(const float4*)&Bs[k][tx<<2];
      acc[0][0] += a4.x*b4.x; acc[0][1] += a4.x*b4.y; acc[0][2] += a4.x*b4.z; acc[0][3] += a4.x*b4.w;
      acc[1][0] += a4.y*b4.x; acc[1][1] += a4.y*b4.y; acc[1][2] += a4.y*b4.z; acc[1][3] += a4.y*b4.w;
      acc[2][0] += a4.z*b4.x; acc[2][1] += a4.z*b4.y; acc[2][2] += a4.z*b4.z; acc[2][3] += a4.z*b4.w;
      acc[3][0] += a4.w*b4.x; acc[3][1] += a4.w*b4.y; acc[3][2] += a4.w*b4.z; acc[3][3] += a4.w*b4.w;
    }
    __syncthreads();
  }
  float bvals[4] = {0.f,0.f,0.f,0.f};
  if (bias){
    #pragma unroll
    for (int j=0;j<4;j++) bvals[j] = bias[col0 + (tx<<2) + j];
  }
  #pragma unroll
  for (int i=0;i<4;i++){
    int row = row0 + (ty<<2) + i;
    size_t off = (size_t)row*N + col0 + (tx<<2);
    float o_[4];
    #pragma unroll
    for (int j=0;j<4;j++){
      float v = acc[i][j] + bvals[j];
      if (RES) v += resid[off + j];
      if (ACT == 1) v = v*0.5f*(1.f + erff(v*0.70710678118f));
      o_[j] = v;
    }
    *(float4*)(Cout + off) = make_float4(o_[0],o_[1],o_[2],o_[3]);
  }
}

// ---------------- Fused attention: one block per (b, head). seq=180, dh=64
// K/V staged to LDS as bf16 (fits 64KB); all-f32 softmax/accumulate.
__global__ __launch_bounds__(TPB) void attn_kernel(const float* __restrict__ qkv,
    float* __restrict__ o){
  __shared__ u16 Kb[192][68];
  __shared__ u16 Vb[180][68];
  __shared__ float pbuf[4][4][192];
  int bh = blockIdx.x; int b = bh/12, h = bh - b*12;
  int tid = threadIdx.x, wave = tid>>6, lane = tid&63;
  const float* base = qkv + (size_t)b*180*2304 + h*64;
  // zero-init Kb rows 180..191 (cols 0..63)
  if (tid < 192){
    int j = 180 + (tid>>4), q4 = (tid&15)<<2;
    *(ushort4*)&Kb[j][q4] = make_ushort4(0,0,0,0);
  }
  for (int idx = tid; idx < 180*16; idx += TPB){
    int j = idx >> 4, q4 = (idx & 15) << 2;
    float4 kv = *(const float4*)(base + j*2304 + 768 + q4);
    float4 vv = *(const float4*)(base + j*2304 + 1536 + q4);
    ushort4 kp; kp.x=f2b(kv.x); kp.y=f2b(kv.y); kp.z=f2b(kv.z); kp.w=f2b(kv.w);
    ushort4 vp; vp.x=f2b(vv.x); vp.y=f2b(vv.y); vp.z=f2b(vv.z); vp.w=f2b(vv.w);
    *(ushort4*)&Kb[j][q4] = kp;
    *(ushort4*)&Vb[j][q4] = vp;
  }
  __syncthreads();
  int j2ok = (lane < 52);   // j2 = lane+128 < 180
  for (int k = 0; k < 12; k++){
    int g = wave*4 + k*16;
    bool valid = (g < 180);
    int gq = valid ? g : 176;
    float q0 = base[(gq+0)*2304 + lane];
    float q1 = base[(gq+1)*2304 + lane];
    float q2 = base[(gq+2)*2304 + lane];
    float q3 = base[(gq+3)*2304 + lane];
    float s[4][3];
    #pragma unroll
    for (int r=0;r<4;r++){ s[r][0]=0.f; s[r][1]=0.f; s[r][2]=0.f; }
    #pragma unroll
    for (int d4=0; d4<16; d4++){
      ushort4 ka = *(const ushort4*)&Kb[lane][d4<<2];
      ushort4 kb = *(const ushort4*)&Kb[lane+64][d4<<2];
      ushort4 kc = *(const ushort4*)&Kb[lane+128][d4<<2];  // rows >=180 are zero
      float kaf[4] = {b2f(ka.x),b2f(ka.y),b2f(ka.z),b2f(ka.w)};
      float kbf[4] = {b2f(kb.x),b2f(kb.y),b2f(kb.z),b2f(kb.w)};
      float kcf[4] = {b2f(kc.x),b2f(kc.y),b2f(kc.z),b2f(kc.w)};
      #pragma unroll
      for (int dd=0; dd<4; dd++){
        int d = (d4<<2)+dd;
        float qa = __shfl(q0, d), qb = __shfl(q1, d);
        float qc = __shfl(q2, d), qd = __shfl(q3, d);
        s[0][0] += qa*kaf[dd]; s[0][1] += qa*kbf[dd]; s[0][2] += qa*kcf[dd];
        s[1][0] += qb*kaf[dd]; s[1][1] += qb*kbf[dd]; s[1][2] += qb*kcf[dd];
        s[2][0] += qc*kaf[dd]; s[2][1] += qc*kbf[dd]; s[2][2] += qc*kcf[dd];
        s[3][0] += qd*kaf[dd]; s[3][1] += qd*kbf[dd]; s[3][2] += qd*kcf[dd];
      }
    }
    #pragma unroll
    for (int r=0;r<4;r++){
      float v0 = s[r][0]*0.125f, v1 = s[r][1]*0.125f;
      float v2 = j2ok ? s[r][2]*0.125f : -1e30f;
      float m = fmaxf(v0, fmaxf(v1, v2));
      #pragma unroll
      for (int off=32; off; off>>=1) m = fmaxf(m, __shfl_xor(m, off));
      float p0 = __expf(v0 - m), p1 = __expf(v1 - m);
      float p2 = j2ok ? __expf(v2 - m) : 0.f;
      float ssum = p0+p1+p2;
      #pragma unroll
      for (int off=32; off; off>>=1) ssum += __shfl_xor(ssum, off);
      float inv = 1.f/ssum;
      pbuf[wave][r][lane]     = p0*inv;
      pbuf[wave][r][lane+64]  = p1*inv;
      pbuf[wave][r][lane+128] = p2*inv;
    }
    __syncthreads();
    float o0=0.f,o1=0.f,o2=0.f,o3=0.f;
    #pragma unroll 3
    for (int j4=0; j4<45; j4++){
      float4 pa = *(const float4*)&pbuf[wave][0][j4<<2];
      float4 pb = *(const float4*)&pbuf[wave][1][j4<<2];
      float4 pc = *(const float4*)&pbuf[wave][2][j4<<2];
      float4 pd = *(const float4*)&pbuf[wave][3][j4<<2];
      int j = j4<<2;
      float va = b2f(Vb[j][lane]),   vb = b2f(Vb[j+1][lane]);
      float vc = b2f(Vb[j+2][lane]), vd = b2f(Vb[j+3][lane]);
      o0 += pa.x*va + pa.y*vb + pa.z*vc + pa.w*vd;
      o1 += pb.x*va + pb.y*vb + pb.z*vc + pb.w*vd;
      o2 += pc.x*va + pc.y*vb + pc.z*vc + pc.w*vd;
      o3 += pd.x*va + pd.y*vb + pd.z*vc + pd.w*vd;
    }
    __syncthreads();
    if (valid){
      float* ob = o + (size_t)(b*180)*768 + h*64 + lane;
      ob[(size_t)(g+0)*768] = o0;
      ob[(size_t)(g+1)*768] = o1;
      ob[(size_t)(g+2)*768] = o2;
      ob[(size_t)(g+3)*768] = o3;
    }
  }
}

// ---------------- PrimaryCaps conv (s2, no pad) fused with capsule-layout write (full batch)
__global__ __launch_bounds__(TPB) void pcaps_kernel(const float* __restrict__ t,
    const float* __restrict__ w, const float* __restrict__ bias, float* __restrict__ caps){
  int gid = blockIdx.x*TPB + threadIdx.x;   // 2,097,152 = 256*256*4*8
  int ox = gid & 7; int oy = (gid>>3)&3; int oc = (gid>>5)&255; int b = gid>>13;
  float acc = bias[oc];
  const float* wp = w + oc*576;
  const float* tb = t + (size_t)b*180*64;
  for (int ic=0; ic<64; ic++){
    #pragma unroll
    for (int dy=0;dy<3;dy++){
      int y = oy*2+dy;
      #pragma unroll
      for (int dx=0;dx<3;dx++){
        int x = ox*2+dx;
        acc += tb[(y*18+x)*64 + ic] * wp[ic*9 + dy*3+dx];
      }
    }
  }
  int grp = oc>>3, e = oc&7;
  caps[((size_t)b*1024 + grp*32 + oy*8 + ox)*8 + e] = acc;
}

// ---------------- squash [B*1024, 8] in place
__global__ __launch_bounds__(TPB) void squash_kernel(float* __restrict__ caps){
  int gid = blockIdx.x*TPB + threadIdx.x;   // 262,144
  float* p = caps + (size_t)gid*8;
  float v[8]; float l2 = 0.f;
  #pragma unroll
  for (int e=0;e<8;e++){ v[e]=p[e]; l2 += v[e]*v[e]; }
  float sc = (l2 > 0.f) ? l2/((1.f+l2)*sqrtf(l2)) : 0.f;
  #pragma unroll
  for (int e=0;e<8;e++) p[e] = v[e]*sc;
}

// ---------------- u[b,i,o] = sum_e caps[b,i,e]*cw[i,e,o]
__global__ __launch_bounds__(TPB) void u_kernel(const float* __restrict__ caps,
    const float* __restrict__ cw, float* __restrict__ u){
  int gid = blockIdx.x*TPB + threadIdx.x;   // 12,582,912
  int o = gid % 48; int i = (gid/48) & 1023; int b = gid/(48*1024);
  const float* cp = caps + ((size_t)b*1024 + i)*8;
  const float* wp = cw + i*384 + o;
  float acc = 0.f;
  #pragma unroll
  for (int e=0;e<8;e++) acc += cp[e]*wp[e*48];
  u[gid] = acc;
}

// ---------------- agreement routing, one block per batch element
__global__ __launch_bounds__(TPB) void routing_kernel(const float* __restrict__ u,
    const float* __restrict__ b_route, float* __restrict__ out){
  __shared__ float bb[3072];
  __shared__ float vsh[48];
  __shared__ float red[4][48];
  __shared__ float ssh[48];
  int b = blockIdx.x, tid = threadIdx.x;
  const float* ub = u + (size_t)b*49152;
  for (int idx=tid; idx<3072; idx+=TPB) bb[idx] = b_route[idx];
  __syncthreads();
  for (int it=0; it<4; it++){
    if (it > 0){
      for (int idx=tid; idx<3072; idx+=TPB){
        int i = idx/3, j = idx - i*3;
        const float* up = ub + i*48 + j*16;
        float s = 0.f;
        #pragma unroll
        for (int e=0;e<16;e++) s += up[e]*vsh[j*16+e];
        bb[idx] += s;
      }
      __syncthreads();
    }
    float acc[48];
    #pragma unroll
    for (int q=0;q<48;q++) acc[q] = 0.f;
    for (int i=tid; i<1024; i+=TPB){
      float b0=bb[i*3], b1=bb[i*3+1], b2v=bb[i*3+2];
      float m = fmaxf(b0, fmaxf(b1, b2v));
      float e0=__expf(b0-m), e1=__expf(b1-m), e2=__expf(b2v-m);
      float inv = 1.f/(e0+e1+e2);
      float c0=e0*inv, c1=e1*inv, c2=e2*inv;
      const float* up = ub + i*48;
      #pragma unroll
      for (int e=0;e<16;e++){
        acc[e]    += c0*up[e];
        acc[16+e] += c1*up[16+e];
        acc[32+e] += c2*up[32+e];
      }
    }
    #pragma unroll
    for (int q=0;q<48;q++){
      float v = acc[q];
      #pragma unroll
      for (int off=32; off; off>>=1) v += __shfl_xor(v, off);
      if ((tid&63)==0) red[tid>>6][q] = v;
    }
    __syncthreads();
    if (tid < 48){
      ssh[tid] = red[0][tid]+red[1][tid]+red[2][tid]+red[3][tid];
    }
    __syncthreads();
    if (tid < 48){
      int j = tid >> 4;
      float l2 = 0.f;
      #pragma unroll
      for (int e=0;e<16;e++) l2 += ssh[j*16+e]*ssh[j*16+e];
      float sc = (l2 > 0.f) ? l2/((1.f+l2)*sqrtf(l2)) : 0.f;
      vsh[tid] = ssh[tid]*sc;
    }
    __syncthreads();
  }
  if (tid < 3){
    float l2 = 0.f;
    #pragma unroll
    for (int e=0;e<16;e++) l2 += vsh[tid*16+e]*vsh[tid*16+e];
    out[b*3+tid] = sqrtf(l2);
  }
}

extern "C" void kernel_launch(void* const* d_in, const int* in_sizes, int n_in,
                              void* d_out, int out_size, void* d_ws, size_t ws_size,
                              hipStream_t stream){
  const float* x       = (const float*)d_in[0];
  const float* conv1_w = (const float*)d_in[1];
  const float* conv2_w = (const float*)d_in[2];
  const float* pos_emb = (const float*)d_in[3];
  const float* ln1_g   = (const float*)d_in[4];
  const float* ln1_b   = (const float*)d_in[5];
  const float* qkv_w   = (const float*)d_in[6];
  const float* out_w   = (const float*)d_in[7];
  const float* out_b   = (const float*)d_in[8];
  const float* ln2_g   = (const float*)d_in[9];
  const float* ln2_b   = (const float*)d_in[10];
  const float* ff1_w   = (const float*)d_in[11];
  const float* ff1_b   = (const float*)d_in[12];
  const float* ff2_w   = (const float*)d_in[13];
  const float* ff2_b   = (const float*)d_in[14];
  const float* pc_w    = (const float*)d_in[15];
  const float* pc_b    = (const float*)d_in[16];
  const float* caps_w  = (const float*)d_in[17];
  const float* b_route = (const float*)d_in[18];
  float* out = (float*)d_out;

  // ---- workspace layout: peak 89.9 MB (8 chunks of 32 batches) ----
  char* ws = (char*)d_ws;
  float* t_buf = (float*)(ws);                 // [46080,64] f32  11,796,480 B (persistent)
  float* h_buf = (float*)(ws + 11796480);      // [5760,64]   f32  1,474,560 B (chunk)
  float* ffh   = (float*)(ws + 13271040);      // [5760,256]  f32  5,898,240 B (chunk)
  float* o_buf = (float*)(ws + 19169280);      // [5760,768]  f32 17,694,720 B (chunk)
  float* qkv   = (float*)(ws + 36864000);      // [5760,2304] f32 53,084,160 B (chunk) ends 89,948,160
  // conv-stage aliases (per chunk, consumed strictly before region reuse)
  float* c1out = (float*)(ws + 11796480);      // [32,64,40,72] f32 23,592,960 B (ends 35,389,440)
  float* p1out = (float*)(ws + 35389440);      // [32,64,20,36] f32  5,898,240 B (ends 41,287,680)
  float* c2out = (float*)(ws + 41287680);      // [32,64,20,36] f32  5,898,240 B (ends 47,185,920)
  float* p2out = (float*)(ws + 47185920);      // [32,64,10,18] f32  1,474,560 B (ends 48,660,480)
  // tail aliases (after transformer, chunk scratch is dead)
  float* caps  = (float*)(ws + 11796480);      // [256,1024,8]  f32  8,388,608 B (ends 20,185,088)
  float* u_buf = (float*)(ws + 20185088);      // [256,1024,48] f32 50,331,648 B (ends 70,516,736)

  const int MC = 5760;                         // rows per chunk = 32*180

  // ---- conv-embed, chunked ----
  for (int c = 0; c < 8; c++){
    const float* xc = x + (size_t)c*32*3*40*72;
    conv1_kernel<<<23040, TPB, 0, stream>>>(xc, conv1_w, c1out);
    maxpool_kernel<<<5760, TPB, 0, stream>>>(c1out, p1out, 40,72,20,36, 1474560);
    conv2_kernel<<<6144, TPB, 0, stream>>>(p1out, conv2_w, c2out);
    maxpool_kernel<<<1440, TPB, 0, stream>>>(c2out, p2out, 20,36,10,18, 368640);
    posadd_kernel<<<1440, TPB, 0, stream>>>(p2out, pos_emb, t_buf + (size_t)c*MC*64);
  }

  // ---- transformer: 24 applications of the shared 12-layer stack, chunked ----
  dim3 gq(36,90), go(1,90), gf1(4,90);
  for (int c = 0; c < 8; c++){
    float* tc = t_buf + (size_t)c*MC*64;
    for (int itr=0; itr<24; itr++){
      int l = itr % 12;
      ln_kernel<<<1440,TPB,0,stream>>>(tc, ln1_g + l*64, ln1_b + l*64, h_buf);
      gemm_kernel<0,false><<<gq,TPB,0,stream>>>(
          h_buf, qkv_w + (size_t)l*147456, nullptr, nullptr, qkv, MC,2304,64);
      attn_kernel<<<384,TPB,0,stream>>>(qkv, o_buf);
      gemm_kernel<0,true><<<go,TPB,0,stream>>>(
          o_buf, out_w + (size_t)l*49152, out_b + l*64, tc, tc, MC,64,768);
      ln_kernel<<<1440,TPB,0,stream>>>(tc, ln2_g + l*64, ln2_b + l*64, h_buf);
      gemm_kernel<1,false><<<gf1,TPB,0,stream>>>(
          h_buf, ff1_w + (size_t)l*16384, ff1_b + l*256, nullptr, ffh, MC,256,64);
      gemm_kernel<0,true><<<go,TPB,0,stream>>>(
          ffh, ff2_w + (size_t)l*16384, ff2_b + l*64, tc, tc, MC,64,256);
    }
  }

  // ---- capsule head ----
  pcaps_kernel<<<8192,TPB,0,stream>>>(t_buf, pc_w, pc_b, caps);
  squash_kernel<<<1024,TPB,0,stream>>>(caps);
  u_kernel<<<49152,TPB,0,stream>>>(caps, caps_w, u_buf);
  routing_kernel<<<256,TPB,0,stream>>>(u_buf, b_route, out);
}

// Round 5
// 24134.473 us; speedup vs baseline: 2.2585x; 2.2585x over previous
//
#include <hip/hip_runtime.h>
#include <hip/hip_bf16.h>
#include <math.h>

#define TPB 256
typedef unsigned short u16;
typedef __attribute__((ext_vector_type(8))) short bf16x8;
typedef __attribute__((ext_vector_type(4))) float f32x4;

__device__ __forceinline__ float b2f(u16 u){ return __uint_as_float(((unsigned)u)<<16); }
__device__ __forceinline__ u16 f2b(float f){
  unsigned x = __float_as_uint(f);
  unsigned r = (x + 0x7fffu + ((x>>16)&1u)) >> 16;
  return (u16)r;
}
__device__ __forceinline__ f32x4 mfma16(bf16x8 a, bf16x8 b, f32x4 c){
  return __builtin_amdgcn_mfma_f32_16x16x32_bf16(a, b, c, 0, 0, 0);
}

// ---------------- Conv1 (per 32-batch chunk)
__global__ __launch_bounds__(TPB) void conv1_kernel(const float* __restrict__ x,
    const float* __restrict__ w, float* __restrict__ out){
  int gid = blockIdx.x*TPB + threadIdx.x;
  int ox = gid % 72; int t1 = gid/72; int oy = t1 % 40; t1 /= 40;
  int oc = t1 & 63; int b = t1 >> 6;
  float wv[27];
  #pragma unroll
  for (int i=0;i<27;i++) wv[i] = w[oc*27+i];
  const float* xb = x + (size_t)b*3*40*72;
  float acc = 0.f;
  #pragma unroll
  for (int dy=0; dy<3; dy++){
    int iy = oy-1+dy; if ((unsigned)iy >= 40u) continue;
    #pragma unroll
    for (int dx=0; dx<3; dx++){
      int ix = ox-1+dx; if ((unsigned)ix >= 72u) continue;
      #pragma unroll
      for (int ic=0; ic<3; ic++)
        acc += xb[(ic*40+iy)*72+ix] * wv[(ic*3+dy)*3+dx];
    }
  }
  out[gid] = fmaxf(acc, 0.f);
}

__global__ __launch_bounds__(TPB) void maxpool_kernel(const float* __restrict__ in,
    float* __restrict__ out, int H, int W, int OH, int OW, int total){
  int gid = blockIdx.x*TPB + threadIdx.x;
  if (gid >= total) return;
  int ox = gid % OW; int t1 = gid / OW; int oy = t1 % OH; int bc = t1 / OH;
  const float* ip = in + (size_t)bc*H*W;
  float m = -INFINITY;
  #pragma unroll
  for (int dy=0; dy<3; dy++){
    int iy = oy*2-1+dy; if ((unsigned)iy >= (unsigned)H) continue;
    #pragma unroll
    for (int dx=0; dx<3; dx++){
      int ix = ox*2-1+dx; if ((unsigned)ix >= (unsigned)W) continue;
      m = fmaxf(m, ip[iy*W+ix]);
    }
  }
  out[gid] = m;
}

__global__ __launch_bounds__(TPB) void conv2_kernel(const float* __restrict__ in,
    const float* __restrict__ w, float* __restrict__ out){
  __shared__ float ws[576];
  int blk = blockIdx.x;
  int sub = blk % 3; int ocb = blk / 3; int oc = ocb & 63; int b = ocb >> 6;
  for (int i = threadIdx.x; i < 576; i += TPB) ws[i] = w[oc*576 + i];
  __syncthreads();
  if (threadIdx.x >= 240) return;
  int pos = sub*240 + threadIdx.x;
  int oy = pos/36, ox = pos%36;
  const float* ib = in + (size_t)b*64*720;
  float acc = 0.f;
  for (int ic=0; ic<64; ic++){
    const float* ip = ib + ic*720;
    const float* wp = ws + ic*9;
    #pragma unroll
    for (int dy=0; dy<3; dy++){
      int iy = oy-1+dy; if ((unsigned)iy >= 20u) continue;
      #pragma unroll
      for (int dx=0; dx<3; dx++){
        int ix = ox-1+dx; if ((unsigned)ix >= 36u) continue;
        acc += ip[iy*36+ix]*wp[dy*3+dx];
      }
    }
  }
  out[(size_t)(b*64+oc)*720 + pos] = fmaxf(acc, 0.f);
}

__global__ __launch_bounds__(TPB) void posadd_kernel(const float* __restrict__ p2,
    const float* __restrict__ pos, float* __restrict__ t){
  int gid = blockIdx.x*TPB + threadIdx.x;
  int d = gid & 63; int n = (gid >> 6) % 180; int b = gid / (180*64);
  t[gid] = p2[(size_t)(b*64+d)*180 + n] + pos[n*64+d];
}

// ---------------- weight transpose+cvt: src[l][R][C] f32 -> dst[l][C][R] bf16
__global__ __launch_bounds__(TPB) void tcvt_kernel(const float* __restrict__ src,
    u16* __restrict__ dst, int R, int C, int total){
  int gid = blockIdx.x*TPB + threadIdx.x;
  if (gid >= total) return;
  int rc = R*C;
  int l = gid / rc; int rem = gid - l*rc; int c = rem / R; int r = rem - c*R;
  dst[gid] = f2b(src[(size_t)l*rc + (size_t)r*C + c]);
}

// ---------------- LayerNorm (dim 64) -> bf16 H
__global__ __launch_bounds__(TPB) void ln_kernel(const float* __restrict__ x,
    const float* __restrict__ g, const float* __restrict__ bta, u16* __restrict__ out){
  int row = blockIdx.x*4 + (threadIdx.x>>6);
  int lane = threadIdx.x & 63;
  float v = x[(size_t)row*64 + lane];
  float s = v;
  #pragma unroll
  for (int off=32; off; off>>=1) s += __shfl_xor(s, off);
  float mean = s * (1.f/64.f);
  float d = v - mean;
  float q = d*d;
  #pragma unroll
  for (int off=32; off; off>>=1) q += __shfl_xor(q, off);
  float r = rsqrtf(q*(1.f/64.f) + 1e-5f);
  out[(size_t)row*64 + lane] = f2b(d*r*g[lane] + bta[lane]);
}

// ---------------- qkv GEMM: Hg[rowbase+5760rows][64] @ W^T[2304][64] -> qkvg[5760][2304] bf16
__global__ __launch_bounds__(TPB) void gemm_qkv(const u16* __restrict__ Hg,
    const u16* __restrict__ W, u16* __restrict__ qkvg, int rowbase){
  int wave = threadIdx.x>>6, lane = threadIdx.x&63, q = lane>>4, li = lane&15;
  int m0 = (blockIdx.x*4 + wave)*16;
  const u16* arow = Hg + (size_t)(rowbase + m0 + li)*64 + q*8;
  bf16x8 a0 = *(const bf16x8*)arow;
  bf16x8 a1 = *(const bf16x8*)(arow + 32);
  int nt0 = blockIdx.y*12;
  for (int nt = nt0; nt < nt0+12; nt++){
    const u16* brow = W + (size_t)(nt*16 + li)*64 + q*8;
    bf16x8 b0 = *(const bf16x8*)brow;
    bf16x8 b1 = *(const bf16x8*)(brow + 32);
    f32x4 c = {0.f,0.f,0.f,0.f};
    c = mfma16(a0, b0, c);
    c = mfma16(a1, b1, c);
    #pragma unroll
    for (int r=0;r<4;r++)
      qkvg[(size_t)(m0 + q*4 + r)*2304 + nt*16 + li] = f2b(c[r]);
  }
}

// ---------------- fused attention per (head, sample): qkvg[5760][2304] -> Og[5760][768]
__global__ __launch_bounds__(TPB) void attn_mfma(const u16* __restrict__ qkvg,
    u16* __restrict__ Og){
  __shared__ u16 VT[64][200];      // V transposed [d][token]
  __shared__ u16 Pw[4][16][200];   // wave-private P panels
  int h = blockIdx.x, s = blockIdx.y;
  int tid = threadIdx.x, wave = tid>>6, lane = tid&63;
  int q = lane>>4, li = lane&15;
  const u16* qb = qkvg + (size_t)s*180*2304;
  // zero-pad VT cols 180..191 (mfma K reads to col 191; P there is 0, avoid 0*NaN)
  for (int idx = tid; idx < 64*12; idx += TPB){
    int d = idx/12, col = 180 + idx - (idx/12)*12;
    VT[d][col] = 0;
  }
  // stage V transposed
  for (int idx = tid; idx < 2880; idx += TPB){
    int tok = idx >> 4, d4 = (idx & 15) << 2;
    ushort4 v = *(const ushort4*)(qb + (size_t)tok*2304 + 1536 + h*64 + d4);
    VT[d4+0][tok] = v.x; VT[d4+1][tok] = v.y; VT[d4+2][tok] = v.z; VT[d4+3][tok] = v.w;
  }
  __syncthreads();
  for (int p = wave; p < 12; p += 4){
    int m0 = p*16;
    int ar = m0 + li; if (ar > 179) ar = 179;
    const u16* qrow = qb + (size_t)ar*2304 + h*64 + q*8;
    bf16x8 a0 = *(const bf16x8*)qrow;
    bf16x8 a1 = *(const bf16x8*)(qrow + 32);
    f32x4 S[12];
    #pragma unroll 4
    for (int t=0;t<12;t++){
      int kr = t*16 + li; if (kr > 179) kr = 179;
      const u16* krow = qb + (size_t)kr*2304 + 768 + h*64 + q*8;
      bf16x8 b0 = *(const bf16x8*)krow;
      bf16x8 b1 = *(const bf16x8*)(krow + 32);
      f32x4 c = {0.f,0.f,0.f,0.f};
      c = mfma16(a0, b0, c);
      c = mfma16(a1, b1, c);
      S[t] = c;
    }
    // scale + mask pad key-columns (col = t*16+li >= 180)
    #pragma unroll
    for (int t=0;t<12;t++){
      #pragma unroll
      for (int r=0;r<4;r++) S[t][r] *= 0.125f;
    }
    if (li >= 4){
      #pragma unroll
      for (int r=0;r<4;r++) S[11][r] = -1e30f;
    }
    // softmax rows (row = q*4+r), reduce across 16-lane group
    #pragma unroll
    for (int r=0;r<4;r++){
      float mx = S[0][r];
      #pragma unroll
      for (int t=1;t<12;t++) mx = fmaxf(mx, S[t][r]);
      #pragma unroll
      for (int off=8; off; off>>=1) mx = fmaxf(mx, __shfl_xor(mx, off));
      float e[12]; float sum = 0.f;
      #pragma unroll
      for (int t=0;t<12;t++){ e[t] = __expf(S[t][r]-mx); sum += e[t]; }
      #pragma unroll
      for (int off=8; off; off>>=1) sum += __shfl_xor(sum, off);
      float inv = 1.f/sum;
      #pragma unroll
      for (int t=0;t<12;t++) Pw[wave][q*4+r][t*16+li] = f2b(e[t]*inv);
    }
    // PV: O panel [16][64]
    bf16x8 ap[6];
    #pragma unroll
    for (int kb=0;kb<6;kb++) ap[kb] = *(const bf16x8*)&Pw[wave][li][kb*32 + q*8];
    #pragma unroll
    for (int nd=0; nd<4; nd++){
      f32x4 c = {0.f,0.f,0.f,0.f};
      #pragma unroll
      for (int kb=0;kb<6;kb++){
        bf16x8 b = *(const bf16x8*)&VT[nd*16+li][kb*32 + q*8];
        c = mfma16(ap[kb], b, c);
      }
      #pragma unroll
      for (int r=0;r<4;r++){
        int row = m0 + q*4 + r;
        if (row < 180)
          Og[(size_t)(s*180+row)*768 + h*64 + nd*16 + li] = f2b(c[r]);
      }
    }
  }
}

// ---------------- out-proj: t[rowbase+..] += Og[5760][768] @ WOT^T + out_b
__global__ __launch_bounds__(64) void gemm_outp(const u16* __restrict__ Og,
    const u16* __restrict__ WOT, const float* __restrict__ outb,
    float* __restrict__ t, int rowbase){
  int m0 = blockIdx.x*16;
  int lane = threadIdx.x, q = lane>>4, li = lane&15;
  f32x4 acc[4];
  #pragma unroll
  for (int nd=0;nd<4;nd++) acc[nd] = (f32x4){0.f,0.f,0.f,0.f};
  for (int kb=0; kb<24; kb++){
    bf16x8 a = *(const bf16x8*)(Og + (size_t)(m0+li)*768 + kb*32 + q*8);
    #pragma unroll
    for (int nd=0;nd<4;nd++){
      bf16x8 b = *(const bf16x8*)(WOT + (size_t)(nd*16+li)*768 + kb*32 + q*8);
      acc[nd] = mfma16(a, b, acc[nd]);
    }
  }
  #pragma unroll
  for (int nd=0;nd<4;nd++){
    int col = nd*16 + li;
    float bv = outb[col];
    #pragma unroll
    for (int r=0;r<4;r++){
      size_t off = (size_t)(rowbase + m0 + q*4 + r)*64 + col;
      t[off] += acc[nd][r] + bv;
    }
  }
}

// ---------------- ff1: G[46080][256] = gelu(Hg @ WF1T^T + b1), bf16 out
__global__ __launch_bounds__(64) void gemm_ff1(const u16* __restrict__ Hg,
    const u16* __restrict__ W, const float* __restrict__ bias, u16* __restrict__ G){
  int m0 = blockIdx.x*16;
  int lane = threadIdx.x, q = lane>>4, li = lane&15;
  const u16* arow = Hg + (size_t)(m0+li)*64 + q*8;
  bf16x8 a0 = *(const bf16x8*)arow;
  bf16x8 a1 = *(const bf16x8*)(arow + 32);
  for (int nt=0; nt<16; nt++){
    const u16* brow = W + (size_t)(nt*16+li)*64 + q*8;
    bf16x8 b0 = *(const bf16x8*)brow;
    bf16x8 b1 = *(const bf16x8*)(brow + 32);
    f32x4 c = {0.f,0.f,0.f,0.f};
    c = mfma16(a0, b0, c);
    c = mfma16(a1, b1, c);
    int col = nt*16 + li;
    float bv = bias[col];
    #pragma unroll
    for (int r=0;r<4;r++){
      float v = c[r] + bv;
      v = v*0.5f*(1.f + erff(v*0.70710678118f));
      G[(size_t)(m0 + q*4 + r)*256 + col] = f2b(v);
    }
  }
}

// ---------------- ff2: t += G @ WF2T^T + b2
__global__ __launch_bounds__(64) void gemm_ff2(const u16* __restrict__ G,
    const u16* __restrict__ W, const float* __restrict__ bias, float* __restrict__ t){
  int m0 = blockIdx.x*16;
  int lane = threadIdx.x, q = lane>>4, li = lane&15;
  f32x4 acc[4];
  #pragma unroll
  for (int nd=0;nd<4;nd++) acc[nd] = (f32x4){0.f,0.f,0.f,0.f};
  for (int kb=0; kb<8; kb++){
    bf16x8 a = *(const bf16x8*)(G + (size_t)(m0+li)*256 + kb*32 + q*8);
    #pragma unroll
    for (int nd=0;nd<4;nd++){
      bf16x8 b = *(const bf16x8*)(W + (size_t)(nd*16+li)*256 + kb*32 + q*8);
      acc[nd] = mfma16(a, b, acc[nd]);
    }
  }
  #pragma unroll
  for (int nd=0;nd<4;nd++){
    int col = nd*16 + li;
    float bv = bias[col];
    #pragma unroll
    for (int r=0;r<4;r++){
      size_t off = (size_t)(m0 + q*4 + r)*64 + col;
      t[off] += acc[nd][r] + bv;
    }
  }
}

// ---------------- capsule head (unchanged f32)
__global__ __launch_bounds__(TPB) void pcaps_kernel(const float* __restrict__ t,
    const float* __restrict__ w, const float* __restrict__ bias, float* __restrict__ caps){
  int gid = blockIdx.x*TPB + threadIdx.x;
  int ox = gid & 7; int oy = (gid>>3)&3; int oc = (gid>>5)&255; int b = gid>>13;
  float acc = bias[oc];
  const float* wp = w + oc*576;
  const float* tb = t + (size_t)b*180*64;
  for (int ic=0; ic<64; ic++){
    #pragma unroll
    for (int dy=0;dy<3;dy++){
      int y = oy*2+dy;
      #pragma unroll
      for (int dx=0;dx<3;dx++){
        int x = ox*2+dx;
        acc += tb[(y*18+x)*64 + ic] * wp[ic*9 + dy*3+dx];
      }
    }
  }
  int grp = oc>>3, e = oc&7;
  caps[((size_t)b*1024 + grp*32 + oy*8 + ox)*8 + e] = acc;
}

__global__ __launch_bounds__(TPB) void squash_kernel(float* __restrict__ caps){
  int gid = blockIdx.x*TPB + threadIdx.x;
  float* p = caps + (size_t)gid*8;
  float v[8]; float l2 = 0.f;
  #pragma unroll
  for (int e=0;e<8;e++){ v[e]=p[e]; l2 += v[e]*v[e]; }
  float sc = (l2 > 0.f) ? l2/((1.f+l2)*sqrtf(l2)) : 0.f;
  #pragma unroll
  for (int e=0;e<8;e++) p[e] = v[e]*sc;
}

__global__ __launch_bounds__(TPB) void u_kernel(const float* __restrict__ caps,
    const float* __restrict__ cw, float* __restrict__ u){
  int gid = blockIdx.x*TPB + threadIdx.x;
  int o = gid % 48; int i = (gid/48) & 1023; int b = gid/(48*1024);
  const float* cp = caps + ((size_t)b*1024 + i)*8;
  const float* wp = cw + i*384 + o;
  float acc = 0.f;
  #pragma unroll
  for (int e=0;e<8;e++) acc += cp[e]*wp[e*48];
  u[gid] = acc;
}

__global__ __launch_bounds__(TPB) void routing_kernel(const float* __restrict__ u,
    const float* __restrict__ b_route, float* __restrict__ out){
  __shared__ float bb[3072];
  __shared__ float vsh[48];
  __shared__ float red[4][48];
  __shared__ float ssh[48];
  int b = blockIdx.x, tid = threadIdx.x;
  const float* ub = u + (size_t)b*49152;
  for (int idx=tid; idx<3072; idx+=TPB) bb[idx] = b_route[idx];
  __syncthreads();
  for (int it=0; it<4; it++){
    if (it > 0){
      for (int idx=tid; idx<3072; idx+=TPB){
        int i = idx/3, j = idx - i*3;
        const float* up = ub + i*48 + j*16;
        float s = 0.f;
        #pragma unroll
        for (int e=0;e<16;e++) s += up[e]*vsh[j*16+e];
        bb[idx] += s;
      }
      __syncthreads();
    }
    float acc[48];
    #pragma unroll
    for (int q2=0;q2<48;q2++) acc[q2] = 0.f;
    for (int i=tid; i<1024; i+=TPB){
      float b0=bb[i*3], b1=bb[i*3+1], b2v=bb[i*3+2];
      float m = fmaxf(b0, fmaxf(b1, b2v));
      float e0=__expf(b0-m), e1=__expf(b1-m), e2=__expf(b2v-m);
      float inv = 1.f/(e0+e1+e2);
      float c0=e0*inv, c1=e1*inv, c2=e2*inv;
      const float* up = ub + i*48;
      #pragma unroll
      for (int e=0;e<16;e++){
        acc[e]    += c0*up[e];
        acc[16+e] += c1*up[16+e];
        acc[32+e] += c2*up[32+e];
      }
    }
    #pragma unroll
    for (int q2=0;q2<48;q2++){
      float v = acc[q2];
      #pragma unroll
      for (int off=32; off; off>>=1) v += __shfl_xor(v, off);
      if ((tid&63)==0) red[tid>>6][q2] = v;
    }
    __syncthreads();
    if (tid < 48) ssh[tid] = red[0][tid]+red[1][tid]+red[2][tid]+red[3][tid];
    __syncthreads();
    if (tid < 48){
      int j = tid >> 4;
      float l2 = 0.f;
      #pragma unroll
      for (int e=0;e<16;e++) l2 += ssh[j*16+e]*ssh[j*16+e];
      float sc = (l2 > 0.f) ? l2/((1.f+l2)*sqrtf(l2)) : 0.f;
      vsh[tid] = ssh[tid]*sc;
    }
    __syncthreads();
  }
  if (tid < 3){
    float l2 = 0.f;
    #pragma unroll
    for (int e=0;e<16;e++) l2 += vsh[tid*16+e]*vsh[tid*16+e];
    out[b*3+tid] = sqrtf(l2);
  }
}

extern "C" void kernel_launch(void* const* d_in, const int* in_sizes, int n_in,
                              void* d_out, int out_size, void* d_ws, size_t ws_size,
                              hipStream_t stream){
  const float* x       = (const float*)d_in[0];
  const float* conv1_w = (const float*)d_in[1];
  const float* conv2_w = (const float*)d_in[2];
  const float* pos_emb = (const float*)d_in[3];
  const float* ln1_g   = (const float*)d_in[4];
  const float* ln1_b   = (const float*)d_in[5];
  const float* qkv_w   = (const float*)d_in[6];
  const float* out_w   = (const float*)d_in[7];
  const float* out_b   = (const float*)d_in[8];
  const float* ln2_g   = (const float*)d_in[9];
  const float* ln2_b   = (const float*)d_in[10];
  const float* ff1_w   = (const float*)d_in[11];
  const float* ff1_b   = (const float*)d_in[12];
  const float* ff2_w   = (const float*)d_in[13];
  const float* ff2_b   = (const float*)d_in[14];
  const float* pc_w    = (const float*)d_in[15];
  const float* pc_b    = (const float*)d_in[16];
  const float* caps_w  = (const float*)d_in[17];
  const float* b_route = (const float*)d_in[18];
  float* out = (float*)d_out;

  // ---- workspace layout: peak 82.2 MB ----
  char* ws = (char*)d_ws;
  float* t_buf = (float*)(ws);                  // [46080,64] f32  0 .. 11,796,480
  u16*  Hg    = (u16*)(ws + 11796480);          // [46080,64] bf16 .. 17,694,720
  u16*  G     = (u16*)(ws + 17694720);          // [46080,256] bf16 .. 41,287,680
  u16*  WQKVT = (u16*)(ws + 41287680);          // [12][2304][64] .. 44,826,624
  u16*  WOT   = (u16*)(ws + 44826624);          // [12][64][768]  .. 46,006,272
  u16*  WF1T  = (u16*)(ws + 46006272);          // [12][256][64]  .. 46,399,488
  u16*  WF2T  = (u16*)(ws + 46399488);          // [12][64][256]  .. 46,792,704
  u16*  qkvg  = (u16*)(ws + 46792704);          // [5760][2304] bf16 chunk .. 73,334,784
  u16*  Og    = (u16*)(ws + 73334784);          // [5760][768]  bf16 chunk .. 82,182,144
  // conv scratch (used before weights/qkvg are written)
  float* c1out = (float*)(ws + 11796480);
  float* p1out = (float*)(ws + 35389440);
  float* c2out = (float*)(ws + 41287680);
  float* p2out = (float*)(ws + 47185920);
  // tail aliases (after transformer)
  float* caps  = (float*)(ws + 11796480);
  float* u_buf = (float*)(ws + 20185088);

  const int MC = 5760;   // rows per chunk = 32*180

  // ---- conv-embed (8 chunks of 32 batches) ----
  for (int c = 0; c < 8; c++){
    const float* xc = x + (size_t)c*32*3*40*72;
    conv1_kernel<<<23040, TPB, 0, stream>>>(xc, conv1_w, c1out);
    maxpool_kernel<<<5760, TPB, 0, stream>>>(c1out, p1out, 40,72,20,36, 1474560);
    conv2_kernel<<<6144, TPB, 0, stream>>>(p1out, conv2_w, c2out);
    maxpool_kernel<<<1440, TPB, 0, stream>>>(c2out, p2out, 20,36,10,18, 368640);
    posadd_kernel<<<1440, TPB, 0, stream>>>(p2out, pos_emb, t_buf + (size_t)c*MC*64);
  }

  // ---- weight prep: f32 [l][R][C] -> bf16 [l][C][R] ----
  tcvt_kernel<<<6912, TPB, 0, stream>>>(qkv_w, WQKVT, 64, 2304, 12*64*2304);
  tcvt_kernel<<<2304, TPB, 0, stream>>>(out_w, WOT, 768, 64, 12*768*64);
  tcvt_kernel<<<768, TPB, 0, stream>>>(ff1_w, WF1T, 64, 256, 12*64*256);
  tcvt_kernel<<<768, TPB, 0, stream>>>(ff2_w, WF2T, 256, 64, 12*256*64);

  // ---- transformer: 24 applications of the shared 12-layer stack ----
  for (int itr=0; itr<24; itr++){
    int l = itr % 12;
    ln_kernel<<<11520, TPB, 0, stream>>>(t_buf, ln1_g + l*64, ln1_b + l*64, Hg);
    for (int c = 0; c < 8; c++){
      gemm_qkv<<<dim3(90,12), TPB, 0, stream>>>(Hg, WQKVT + (size_t)l*2304*64, qkvg, c*MC);
      attn_mfma<<<dim3(12,32), TPB, 0, stream>>>(qkvg, Og);
      gemm_outp<<<360, 64, 0, stream>>>(Og, WOT + (size_t)l*64*768, out_b + l*64, t_buf, c*MC);
    }
    ln_kernel<<<11520, TPB, 0, stream>>>(t_buf, ln2_g + l*64, ln2_b + l*64, Hg);
    gemm_ff1<<<2880, 64, 0, stream>>>(Hg, WF1T + (size_t)l*256*64, ff1_b + l*256, G);
    gemm_ff2<<<2880, 64, 0, stream>>>(G, WF2T + (size_t)l*64*256, ff2_b + l*64, t_buf);
  }

  // ---- capsule head ----
  pcaps_kernel<<<8192, TPB, 0, stream>>>(t_buf, pc_w, pc_b, caps);
  squash_kernel<<<1024, TPB, 0, stream>>>(caps);
  u_kernel<<<49152, TPB, 0, stream>>>(caps, caps_w, u_buf);
  routing_kernel<<<256, TPB, 0, stream>>>(u_buf, b_route, out);
}

// Round 6
// 9253.329 us; speedup vs baseline: 5.8907x; 2.6082x over previous
//
#include <hip/hip_runtime.h>
#include <hip/hip_bf16.h>
#include <math.h>

#define TPB 256
typedef unsigned short u16;
typedef __attribute__((ext_vector_type(8))) short bf16x8;
typedef __attribute__((ext_vector_type(4))) float f32x4;

__device__ __forceinline__ float b2f(u16 u){ return __uint_as_float(((unsigned)u)<<16); }
__device__ __forceinline__ u16 f2b(float f){
  unsigned x = __float_as_uint(f);
  unsigned r = (x + 0x7fffu + ((x>>16)&1u)) >> 16;
  return (u16)r;
}
__device__ __forceinline__ f32x4 mfma16(bf16x8 a, bf16x8 b, f32x4 c){
  return __builtin_amdgcn_mfma_f32_16x16x32_bf16(a, b, c, 0, 0, 0);
}

// ---------------- Conv1 (per 64-batch chunk)
__global__ __launch_bounds__(TPB) void conv1_kernel(const float* __restrict__ x,
    const float* __restrict__ w, float* __restrict__ out){
  int gid = blockIdx.x*TPB + threadIdx.x;
  int ox = gid % 72; int t1 = gid/72; int oy = t1 % 40; t1 /= 40;
  int oc = t1 & 63; int b = t1 >> 6;
  float wv[27];
  #pragma unroll
  for (int i=0;i<27;i++) wv[i] = w[oc*27+i];
  const float* xb = x + (size_t)b*3*40*72;
  float acc = 0.f;
  #pragma unroll
  for (int dy=0; dy<3; dy++){
    int iy = oy-1+dy; if ((unsigned)iy >= 40u) continue;
    #pragma unroll
    for (int dx=0; dx<3; dx++){
      int ix = ox-1+dx; if ((unsigned)ix >= 72u) continue;
      #pragma unroll
      for (int ic=0; ic<3; ic++)
        acc += xb[(ic*40+iy)*72+ix] * wv[(ic*3+dy)*3+dx];
    }
  }
  out[gid] = fmaxf(acc, 0.f);
}

__global__ __launch_bounds__(TPB) void maxpool_kernel(const float* __restrict__ in,
    float* __restrict__ out, int H, int W, int OH, int OW, int total){
  int gid = blockIdx.x*TPB + threadIdx.x;
  if (gid >= total) return;
  int ox = gid % OW; int t1 = gid / OW; int oy = t1 % OH; int bc = t1 / OH;
  const float* ip = in + (size_t)bc*H*W;
  float m = -INFINITY;
  #pragma unroll
  for (int dy=0; dy<3; dy++){
    int iy = oy*2-1+dy; if ((unsigned)iy >= (unsigned)H) continue;
    #pragma unroll
    for (int dx=0; dx<3; dx++){
      int ix = ox*2-1+dx; if ((unsigned)ix >= (unsigned)W) continue;
      m = fmaxf(m, ip[iy*W+ix]);
    }
  }
  out[gid] = m;
}

__global__ __launch_bounds__(TPB) void conv2_kernel(const float* __restrict__ in,
    const float* __restrict__ w, float* __restrict__ out){
  __shared__ float ws[576];
  int blk = blockIdx.x;
  int sub = blk % 3; int ocb = blk / 3; int oc = ocb & 63; int b = ocb >> 6;
  for (int i = threadIdx.x; i < 576; i += TPB) ws[i] = w[oc*576 + i];
  __syncthreads();
  if (threadIdx.x >= 240) return;
  int pos = sub*240 + threadIdx.x;
  int oy = pos/36, ox = pos%36;
  const float* ib = in + (size_t)b*64*720;
  float acc = 0.f;
  for (int ic=0; ic<64; ic++){
    const float* ip = ib + ic*720;
    const float* wp = ws + ic*9;
    #pragma unroll
    for (int dy=0; dy<3; dy++){
      int iy = oy-1+dy; if ((unsigned)iy >= 20u) continue;
      #pragma unroll
      for (int dx=0; dx<3; dx++){
        int ix = ox-1+dx; if ((unsigned)ix >= 36u) continue;
        acc += ip[iy*36+ix]*wp[dy*3+dx];
      }
    }
  }
  out[(size_t)(b*64+oc)*720 + pos] = fmaxf(acc, 0.f);
}

__global__ __launch_bounds__(TPB) void posadd_kernel(const float* __restrict__ p2,
    const float* __restrict__ pos, float* __restrict__ t){
  int gid = blockIdx.x*TPB + threadIdx.x;
  int d = gid & 63; int n = (gid >> 6) % 180; int b = gid / (180*64);
  t[gid] = p2[(size_t)(b*64+d)*180 + n] + pos[n*64+d];
}

// ---------------- weight transpose+cvt: src[l][R][C] f32 -> dst[l][C][R] bf16
__global__ __launch_bounds__(TPB) void tcvt_kernel(const float* __restrict__ src,
    u16* __restrict__ dst, int R, int C, int total){
  int gid = blockIdx.x*TPB + threadIdx.x;
  if (gid >= total) return;
  int rc = R*C;
  int l = gid / rc; int rem = gid - l*rc; int c = rem / R; int r = rem - c*R;
  dst[gid] = f2b(src[(size_t)l*rc + (size_t)r*C + c]);
}

// ---------------- LayerNorm (dim 64) -> bf16 H
__global__ __launch_bounds__(TPB) void ln_kernel(const float* __restrict__ x,
    const float* __restrict__ g, const float* __restrict__ bta, u16* __restrict__ out){
  int row = blockIdx.x*4 + (threadIdx.x>>6);
  int lane = threadIdx.x & 63;
  float v = x[(size_t)row*64 + lane];
  float s = v;
  #pragma unroll
  for (int off=32; off; off>>=1) s += __shfl_xor(s, off);
  float mean = s * (1.f/64.f);
  float d = v - mean;
  float q = d*d;
  #pragma unroll
  for (int off=32; off; off>>=1) q += __shfl_xor(q, off);
  float r = rsqrtf(q*(1.f/64.f) + 1e-5f);
  out[(size_t)row*64 + lane] = f2b(d*r*g[lane] + bta[lane]);
}

// ---------------- fused QKV-proj + attention: one block per (head, sample)
// Hg [46080][64] bf16; W = WQKVT layer slice [2304][64]; Og [46080][768] bf16
__global__ __launch_bounds__(TPB) void attn_fused(const u16* __restrict__ Hg,
    const u16* __restrict__ W, u16* __restrict__ Og){
  __shared__ u16 Kl[192][66];     // K [token][d]
  __shared__ u16 VT[64][200];     // V^T [d][token]
  __shared__ u16 Pw[4][16][104];  // wave-private transpose panel (Q, then P halves)
  int h = blockIdx.x, s = blockIdx.y;
  int tid = threadIdx.x, wave = tid>>6, lane = tid&63;
  int q = lane>>4, li = lane&15;
  const u16* Hb = Hg + (size_t)s*180*64;
  const u16* Wq = W + (size_t)(h*64)*64;
  const u16* Wk = W + (size_t)(768 + h*64)*64;
  const u16* Wv = W + (size_t)(1536 + h*64)*64;
  // ---- phase 1: K and V^T into LDS (rows >=180 are clamped clones, masked later)
  for (int p = wave; p < 12; p += 4){
    int m0 = p*16;
    int ar = m0 + li; if (ar > 179) ar = 179;
    const u16* hrow = Hb + (size_t)ar*64 + q*8;
    bf16x8 a0 = *(const bf16x8*)hrow;
    bf16x8 a1 = *(const bf16x8*)(hrow+32);
    #pragma unroll
    for (int nt=0; nt<4; nt++){
      const u16* kr = Wk + (size_t)(nt*16+li)*64 + q*8;
      bf16x8 b0 = *(const bf16x8*)kr;
      bf16x8 b1 = *(const bf16x8*)(kr+32);
      f32x4 ck = {0.f,0.f,0.f,0.f};
      ck = mfma16(a0,b0,ck); ck = mfma16(a1,b1,ck);
      #pragma unroll
      for (int r=0;r<4;r++) Kl[m0+q*4+r][nt*16+li] = f2b(ck[r]);
      const u16* vr = Wv + (size_t)(nt*16+li)*64 + q*8;
      bf16x8 d0 = *(const bf16x8*)vr;
      bf16x8 d1 = *(const bf16x8*)(vr+32);
      f32x4 cv = {0.f,0.f,0.f,0.f};
      cv = mfma16(a0,d0,cv); cv = mfma16(a1,d1,cv);
      #pragma unroll
      for (int r=0;r<4;r++) VT[nt*16+li][m0+q*4+r] = f2b(cv[r]);
    }
  }
  __syncthreads();
  // ---- phase 2: per M-tile Q -> S -> softmax -> PV
  for (int p = wave; p < 12; p += 4){
    int m0 = p*16;
    int ar = m0 + li; if (ar > 179) ar = 179;
    const u16* hrow = Hb + (size_t)ar*64 + q*8;
    bf16x8 a0 = *(const bf16x8*)hrow;
    bf16x8 a1 = *(const bf16x8*)(hrow+32);
    // Q tile (pre-scaled) into panel, C-layout -> A-layout
    #pragma unroll
    for (int nt=0; nt<4; nt++){
      const u16* qr = Wq + (size_t)(nt*16+li)*64 + q*8;
      bf16x8 b0 = *(const bf16x8*)qr;
      bf16x8 b1 = *(const bf16x8*)(qr+32);
      f32x4 c = {0.f,0.f,0.f,0.f};
      c = mfma16(a0,b0,c); c = mfma16(a1,b1,c);
      #pragma unroll
      for (int r=0;r<4;r++) Pw[wave][q*4+r][nt*16+li] = f2b(c[r]*0.125f);
    }
    bf16x8 qa0 = *(const bf16x8*)&Pw[wave][li][q*8];
    bf16x8 qa1 = *(const bf16x8*)&Pw[wave][li][32+q*8];
    f32x4 S[12];
    #pragma unroll
    for (int t=0;t<12;t++){
      bf16x8 b0 = *(const bf16x8*)&Kl[t*16+li][q*8];
      bf16x8 b1 = *(const bf16x8*)&Kl[t*16+li][32+q*8];
      f32x4 c = {0.f,0.f,0.f,0.f};
      c = mfma16(qa0,b0,c); c = mfma16(qa1,b1,c);
      S[t] = c;
    }
    if (li >= 4){ S[11][0]=-1e30f; S[11][1]=-1e30f; S[11][2]=-1e30f; S[11][3]=-1e30f; }
    // softmax per row r (16-lane group holds 16 key-cols per t)
    float eB[4][6];
    #pragma unroll
    for (int r=0;r<4;r++){
      float mx = S[0][r];
      #pragma unroll
      for (int t=1;t<12;t++) mx = fmaxf(mx, S[t][r]);
      #pragma unroll
      for (int off=8; off; off>>=1) mx = fmaxf(mx, __shfl_xor(mx, off));
      float e[12]; float sum = 0.f;
      #pragma unroll
      for (int t=0;t<12;t++){ e[t] = __expf(S[t][r]-mx); sum += e[t]; }
      #pragma unroll
      for (int off=8; off; off>>=1) sum += __shfl_xor(sum, off);
      float inv = 1.f/sum;
      #pragma unroll
      for (int t=0;t<6;t++) Pw[wave][q*4+r][t*16+li] = f2b(e[t]*inv);
      #pragma unroll
      for (int t=0;t<6;t++) eB[r][t] = e[6+t]*inv;
    }
    f32x4 c4[4];
    #pragma unroll
    for (int nd=0;nd<4;nd++) c4[nd] = (f32x4){0.f,0.f,0.f,0.f};
    { // PV pass A: key-cols 0..95
      bf16x8 pa[3];
      #pragma unroll
      for (int kb=0;kb<3;kb++) pa[kb] = *(const bf16x8*)&Pw[wave][li][kb*32+q*8];
      #pragma unroll
      for (int nd=0;nd<4;nd++){
        #pragma unroll
        for (int kb=0;kb<3;kb++){
          bf16x8 b = *(const bf16x8*)&VT[nd*16+li][kb*32+q*8];
          c4[nd] = mfma16(pa[kb], b, c4[nd]);
        }
      }
    }
    #pragma unroll
    for (int r=0;r<4;r++){
      #pragma unroll
      for (int t=0;t<6;t++) Pw[wave][q*4+r][t*16+li] = f2b(eB[r][t]);
    }
    { // PV pass B: key-cols 96..191
      bf16x8 pa[3];
      #pragma unroll
      for (int kb=0;kb<3;kb++) pa[kb] = *(const bf16x8*)&Pw[wave][li][kb*32+q*8];
      #pragma unroll
      for (int nd=0;nd<4;nd++){
        #pragma unroll
        for (int kb=0;kb<3;kb++){
          bf16x8 b = *(const bf16x8*)&VT[nd*16+li][96+kb*32+q*8];
          c4[nd] = mfma16(pa[kb], b, c4[nd]);
        }
      }
    }
    #pragma unroll
    for (int nd=0; nd<4; nd++){
      #pragma unroll
      for (int r=0;r<4;r++){
        int row = m0 + q*4 + r;
        if (row < 180)
          Og[(size_t)(s*180+row)*768 + h*64 + nd*16 + li] = f2b(c4[nd][r]);
      }
    }
  }
}

// ---------------- out-proj (full batch): t += Og @ WOT^T + out_b
__global__ __launch_bounds__(TPB) void gemm_outp(const u16* __restrict__ Og,
    const u16* __restrict__ WOT, const float* __restrict__ outb,
    float* __restrict__ t){
  int wave = threadIdx.x>>6, lane = threadIdx.x&63, q = lane>>4, li = lane&15;
  int m0 = blockIdx.x*64 + wave*16;
  f32x4 acc[4];
  #pragma unroll
  for (int nd=0;nd<4;nd++) acc[nd] = (f32x4){0.f,0.f,0.f,0.f};
  for (int kb=0; kb<24; kb++){
    bf16x8 a = *(const bf16x8*)(Og + (size_t)(m0+li)*768 + kb*32 + q*8);
    #pragma unroll
    for (int nd=0;nd<4;nd++){
      bf16x8 b = *(const bf16x8*)(WOT + (size_t)(nd*16+li)*768 + kb*32 + q*8);
      acc[nd] = mfma16(a, b, acc[nd]);
    }
  }
  #pragma unroll
  for (int nd=0;nd<4;nd++){
    int col = nd*16 + li;
    float bv = outb[col];
    #pragma unroll
    for (int r=0;r<4;r++){
      size_t off = (size_t)(m0 + q*4 + r)*64 + col;
      t[off] += acc[nd][r] + bv;
    }
  }
}

// ---------------- ff1 (full batch): G = gelu(Hg @ WF1T^T + b1) bf16
__global__ __launch_bounds__(TPB) void gemm_ff1(const u16* __restrict__ Hg,
    const u16* __restrict__ W, const float* __restrict__ bias, u16* __restrict__ G){
  int wave = threadIdx.x>>6, lane = threadIdx.x&63, q = lane>>4, li = lane&15;
  int m0 = blockIdx.x*64 + wave*16;
  const u16* arow = Hg + (size_t)(m0+li)*64 + q*8;
  bf16x8 a0 = *(const bf16x8*)arow;
  bf16x8 a1 = *(const bf16x8*)(arow + 32);
  for (int nt=0; nt<16; nt++){
    const u16* brow = W + (size_t)(nt*16+li)*64 + q*8;
    bf16x8 b0 = *(const bf16x8*)brow;
    bf16x8 b1 = *(const bf16x8*)(brow + 32);
    f32x4 c = {0.f,0.f,0.f,0.f};
    c = mfma16(a0, b0, c);
    c = mfma16(a1, b1, c);
    int col = nt*16 + li;
    float bv = bias[col];
    #pragma unroll
    for (int r=0;r<4;r++){
      float v = c[r] + bv;
      v = v*0.5f*(1.f + erff(v*0.70710678118f));
      G[(size_t)(m0 + q*4 + r)*256 + col] = f2b(v);
    }
  }
}

// ---------------- ff2 (full batch): t += G @ WF2T^T + b2
__global__ __launch_bounds__(TPB) void gemm_ff2(const u16* __restrict__ G,
    const u16* __restrict__ W, const float* __restrict__ bias, float* __restrict__ t){
  int wave = threadIdx.x>>6, lane = threadIdx.x&63, q = lane>>4, li = lane&15;
  int m0 = blockIdx.x*64 + wave*16;
  f32x4 acc[4];
  #pragma unroll
  for (int nd=0;nd<4;nd++) acc[nd] = (f32x4){0.f,0.f,0.f,0.f};
  for (int kb=0; kb<8; kb++){
    bf16x8 a = *(const bf16x8*)(G + (size_t)(m0+li)*256 + kb*32 + q*8);
    #pragma unroll
    for (int nd=0;nd<4;nd++){
      bf16x8 b = *(const bf16x8*)(W + (size_t)(nd*16+li)*256 + kb*32 + q*8);
      acc[nd] = mfma16(a, b, acc[nd]);
    }
  }
  #pragma unroll
  for (int nd=0;nd<4;nd++){
    int col = nd*16 + li;
    float bv = bias[col];
    #pragma unroll
    for (int r=0;r<4;r++){
      size_t off = (size_t)(m0 + q*4 + r)*64 + col;
      t[off] += acc[nd][r] + bv;
    }
  }
}

// ---------------- capsule head (f32)
__global__ __launch_bounds__(TPB) void pcaps_kernel(const float* __restrict__ t,
    const float* __restrict__ w, const float* __restrict__ bias, float* __restrict__ caps){
  int gid = blockIdx.x*TPB + threadIdx.x;
  int ox = gid & 7; int oy = (gid>>3)&3; int oc = (gid>>5)&255; int b = gid>>13;
  float acc = bias[oc];
  const float* wp = w + oc*576;
  const float* tb = t + (size_t)b*180*64;
  for (int ic=0; ic<64; ic++){
    #pragma unroll
    for (int dy=0;dy<3;dy++){
      int y = oy*2+dy;
      #pragma unroll
      for (int dx=0;dx<3;dx++){
        int x = ox*2+dx;
        acc += tb[(y*18+x)*64 + ic] * wp[ic*9 + dy*3+dx];
      }
    }
  }
  int grp = oc>>3, e = oc&7;
  caps[((size_t)b*1024 + grp*32 + oy*8 + ox)*8 + e] = acc;
}

__global__ __launch_bounds__(TPB) void squash_kernel(float* __restrict__ caps){
  int gid = blockIdx.x*TPB + threadIdx.x;
  float* p = caps + (size_t)gid*8;
  float v[8]; float l2 = 0.f;
  #pragma unroll
  for (int e=0;e<8;e++){ v[e]=p[e]; l2 += v[e]*v[e]; }
  float sc = (l2 > 0.f) ? l2/((1.f+l2)*sqrtf(l2)) : 0.f;
  #pragma unroll
  for (int e=0;e<8;e++) p[e] = v[e]*sc;
}

__global__ __launch_bounds__(TPB) void u_kernel(const float* __restrict__ caps,
    const float* __restrict__ cw, float* __restrict__ u){
  int gid = blockIdx.x*TPB + threadIdx.x;
  int o = gid % 48; int i = (gid/48) & 1023; int b = gid/(48*1024);
  const float* cp = caps + ((size_t)b*1024 + i)*8;
  const float* wp = cw + i*384 + o;
  float acc = 0.f;
  #pragma unroll
  for (int e=0;e<8;e++) acc += cp[e]*wp[e*48];
  u[gid] = acc;
}

__global__ __launch_bounds__(TPB) void routing_kernel(const float* __restrict__ u,
    const float* __restrict__ b_route, float* __restrict__ out){
  __shared__ float bb[3072];
  __shared__ float vsh[48];
  __shared__ float red[4][48];
  __shared__ float ssh[48];
  int b = blockIdx.x, tid = threadIdx.x;
  const float* ub = u + (size_t)b*49152;
  for (int idx=tid; idx<3072; idx+=TPB) bb[idx] = b_route[idx];
  __syncthreads();
  for (int it=0; it<4; it++){
    if (it > 0){
      for (int idx=tid; idx<3072; idx+=TPB){
        int i = idx/3, j = idx - i*3;
        const float* up = ub + i*48 + j*16;
        float s = 0.f;
        #pragma unroll
        for (int e=0;e<16;e++) s += up[e]*vsh[j*16+e];
        bb[idx] += s;
      }
      __syncthreads();
    }
    float acc[48];
    #pragma unroll
    for (int q2=0;q2<48;q2++) acc[q2] = 0.f;
    for (int i=tid; i<1024; i+=TPB){
      float b0=bb[i*3], b1=bb[i*3+1], b2v=bb[i*3+2];
      float m = fmaxf(b0, fmaxf(b1, b2v));
      float e0=__expf(b0-m), e1=__expf(b1-m), e2=__expf(b2v-m);
      float inv = 1.f/(e0+e1+e2);
      float c0=e0*inv, c1=e1*inv, c2=e2*inv;
      const float* up = ub + i*48;
      #pragma unroll
      for (int e=0;e<16;e++){
        acc[e]    += c0*up[e];
        acc[16+e] += c1*up[16+e];
        acc[32+e] += c2*up[32+e];
      }
    }
    #pragma unroll
    for (int q2=0;q2<48;q2++){
      float v = acc[q2];
      #pragma unroll
      for (int off=32; off; off>>=1) v += __shfl_xor(v, off);
      if ((tid&63)==0) red[tid>>6][q2] = v;
    }
    __syncthreads();
    if (tid < 48) ssh[tid] = red[0][tid]+red[1][tid]+red[2][tid]+red[3][tid];
    __syncthreads();
    if (tid < 48){
      int j = tid >> 4;
      float l2 = 0.f;
      #pragma unroll
      for (int e=0;e<16;e++) l2 += ssh[j*16+e]*ssh[j*16+e];
      float sc = (l2 > 0.f) ? l2/((1.f+l2)*sqrtf(l2)) : 0.f;
      vsh[tid] = ssh[tid]*sc;
    }
    __syncthreads();
  }
  if (tid < 3){
    float l2 = 0.f;
    #pragma unroll
    for (int e=0;e<16;e++) l2 += vsh[tid*16+e]*vsh[tid*16+e];
    out[b*3+tid] = sqrtf(l2);
  }
}

extern "C" void kernel_launch(void* const* d_in, const int* in_sizes, int n_in,
                              void* d_out, int out_size, void* d_ws, size_t ws_size,
                              hipStream_t stream){
  const float* x       = (const float*)d_in[0];
  const float* conv1_w = (const float*)d_in[1];
  const float* conv2_w = (const float*)d_in[2];
  const float* pos_emb = (const float*)d_in[3];
  const float* ln1_g   = (const float*)d_in[4];
  const float* ln1_b   = (const float*)d_in[5];
  const float* qkv_w   = (const float*)d_in[6];
  const float* out_w   = (const float*)d_in[7];
  const float* out_b   = (const float*)d_in[8];
  const float* ln2_g   = (const float*)d_in[9];
  const float* ln2_b   = (const float*)d_in[10];
  const float* ff1_w   = (const float*)d_in[11];
  const float* ff1_b   = (const float*)d_in[12];
  const float* ff2_w   = (const float*)d_in[13];
  const float* ff2_b   = (const float*)d_in[14];
  const float* pc_w    = (const float*)d_in[15];
  const float* pc_b    = (const float*)d_in[16];
  const float* caps_w  = (const float*)d_in[17];
  const float* b_route = (const float*)d_in[18];
  float* out = (float*)d_out;

  // ---- workspace: peak 93,978,624 B (< 97.3 MB proven safe) ----
  char* ws = (char*)d_ws;
  float* t_buf = (float*)(ws);                  // [46080,64] f32   0 .. 11,796,480
  u16*  Hg    = (u16*)(ws + 11796480);          // [46080,64] bf16  .. 17,694,720
  u16*  WQKVT = (u16*)(ws + 17694720);          // [12][2304][64]   .. 21,233,664
  u16*  WOT   = (u16*)(ws + 21233664);          // [12][64][768]    .. 22,413,312
  u16*  WF1T  = (u16*)(ws + 22413312);          // [12][256][64]    .. 22,806,528
  u16*  WF2T  = (u16*)(ws + 22806528);          // [12][64][256]    .. 23,199,744
  char* win   = ws + 23199744;                  // 70,778,880 B window .. 93,978,624
  u16*  Og    = (u16*)win;                      // [46080][768] bf16 (attn<->outp)
  u16*  G     = (u16*)win;                      // [46080][256] bf16 (ff1<->ff2)
  // conv scratch inside window (64-sample chunks)
  float* c1out = (float*)(win);                 // 47,185,920
  float* p1out = (float*)(win + 47185920);      // 11,796,480
  float* c2out = (float*)(win + 58982400);      // 11,796,480 (ends exactly at window end)
  float* p2out = (float*)(win + 47185920);      //  2,949,120 (p1out dead by then)
  // tail inside window
  float* caps  = (float*)(win);                 //  8,388,608
  float* u_buf = (float*)(win + 8388608);       // 50,331,648

  // ---- conv-embed (4 chunks of 64 samples) ----
  for (int c = 0; c < 4; c++){
    const float* xc = x + (size_t)c*64*3*40*72;
    conv1_kernel<<<46080, TPB, 0, stream>>>(xc, conv1_w, c1out);
    maxpool_kernel<<<11520, TPB, 0, stream>>>(c1out, p1out, 40,72,20,36, 2949120);
    conv2_kernel<<<12288, TPB, 0, stream>>>(p1out, conv2_w, c2out);
    maxpool_kernel<<<2880, TPB, 0, stream>>>(c2out, p2out, 20,36,10,18, 737280);
    posadd_kernel<<<2880, TPB, 0, stream>>>(p2out, pos_emb, t_buf + (size_t)c*11520*64);
  }

  // ---- weight prep: f32 [l][R][C] -> bf16 [l][C][R] ----
  tcvt_kernel<<<6912, TPB, 0, stream>>>(qkv_w, WQKVT, 64, 2304, 12*64*2304);
  tcvt_kernel<<<2304, TPB, 0, stream>>>(out_w, WOT, 768, 64, 12*768*64);
  tcvt_kernel<<<768, TPB, 0, stream>>>(ff1_w, WF1T, 64, 256, 12*64*256);
  tcvt_kernel<<<768, TPB, 0, stream>>>(ff2_w, WF2T, 256, 64, 12*256*64);

  // ---- transformer: 24 applications of the shared 12-layer stack (full batch) ----
  for (int itr=0; itr<24; itr++){
    int l = itr % 12;
    ln_kernel<<<11520, TPB, 0, stream>>>(t_buf, ln1_g + l*64, ln1_b + l*64, Hg);
    attn_fused<<<dim3(12,256), TPB, 0, stream>>>(Hg, WQKVT + (size_t)l*2304*64, Og);
    gemm_outp<<<720, TPB, 0, stream>>>(Og, WOT + (size_t)l*64*768, out_b + l*64, t_buf);
    ln_kernel<<<11520, TPB, 0, stream>>>(t_buf, ln2_g + l*64, ln2_b + l*64, Hg);
    gemm_ff1<<<720, TPB, 0, stream>>>(Hg, WF1T + (size_t)l*256*64, ff1_b + l*256, G);
    gemm_ff2<<<720, TPB, 0, stream>>>(G, WF2T + (size_t)l*64*256, ff2_b + l*64, t_buf);
  }

  // ---- capsule head ----
  pcaps_kernel<<<8192, TPB, 0, stream>>>(t_buf, pc_w, pc_b, caps);
  squash_kernel<<<1024, TPB, 0, stream>>>(caps);
  u_kernel<<<49152, TPB, 0, stream>>>(caps, caps_w, u_buf);
  routing_kernel<<<256, TPB, 0, stream>>>(u_buf, b_route, out);
}

// Round 7
// 7584.325 us; speedup vs baseline: 7.1870x; 1.2201x over previous
//
#include <hip/hip_runtime.h>
#include <hip/hip_bf16.h>
#include <math.h>

#define TPB 256
typedef unsigned short u16;
typedef __attribute__((ext_vector_type(8))) short bf16x8;
typedef __attribute__((ext_vector_type(4))) float f32x4;

__device__ __forceinline__ float b2f(u16 u){ return __uint_as_float(((unsigned)u)<<16); }
__device__ __forceinline__ u16 f2b(float f){
  unsigned x = __float_as_uint(f);
  unsigned r = (x + 0x7fffu + ((x>>16)&1u)) >> 16;
  return (u16)r;
}
__device__ __forceinline__ f32x4 mfma16(bf16x8 a, bf16x8 b, f32x4 c){
  return __builtin_amdgcn_mfma_f32_16x16x32_bf16(a, b, c, 0, 0, 0);
}

// ---------------- Conv1 (per 64-batch chunk)
__global__ __launch_bounds__(TPB) void conv1_kernel(const float* __restrict__ x,
    const float* __restrict__ w, float* __restrict__ out){
  int gid = blockIdx.x*TPB + threadIdx.x;
  int ox = gid % 72; int t1 = gid/72; int oy = t1 % 40; t1 /= 40;
  int oc = t1 & 63; int b = t1 >> 6;
  float wv[27];
  #pragma unroll
  for (int i=0;i<27;i++) wv[i] = w[oc*27+i];
  const float* xb = x + (size_t)b*3*40*72;
  float acc = 0.f;
  #pragma unroll
  for (int dy=0; dy<3; dy++){
    int iy = oy-1+dy; if ((unsigned)iy >= 40u) continue;
    #pragma unroll
    for (int dx=0; dx<3; dx++){
      int ix = ox-1+dx; if ((unsigned)ix >= 72u) continue;
      #pragma unroll
      for (int ic=0; ic<3; ic++)
        acc += xb[(ic*40+iy)*72+ix] * wv[(ic*3+dy)*3+dx];
    }
  }
  out[gid] = fmaxf(acc, 0.f);
}

__global__ __launch_bounds__(TPB) void maxpool_kernel(const float* __restrict__ in,
    float* __restrict__ out, int H, int W, int OH, int OW, int total){
  int gid = blockIdx.x*TPB + threadIdx.x;
  if (gid >= total) return;
  int ox = gid % OW; int t1 = gid / OW; int oy = t1 % OH; int bc = t1 / OH;
  const float* ip = in + (size_t)bc*H*W;
  float m = -INFINITY;
  #pragma unroll
  for (int dy=0; dy<3; dy++){
    int iy = oy*2-1+dy; if ((unsigned)iy >= (unsigned)H) continue;
    #pragma unroll
    for (int dx=0; dx<3; dx++){
      int ix = ox*2-1+dx; if ((unsigned)ix >= (unsigned)W) continue;
      m = fmaxf(m, ip[iy*W+ix]);
    }
  }
  out[gid] = m;
}

__global__ __launch_bounds__(TPB) void conv2_kernel(const float* __restrict__ in,
    const float* __restrict__ w, float* __restrict__ out){
  __shared__ float ws[576];
  int blk = blockIdx.x;
  int sub = blk % 3; int ocb = blk / 3; int oc = ocb & 63; int b = ocb >> 6;
  for (int i = threadIdx.x; i < 576; i += TPB) ws[i] = w[oc*576 + i];
  __syncthreads();
  if (threadIdx.x >= 240) return;
  int pos = sub*240 + threadIdx.x;
  int oy = pos/36, ox = pos%36;
  const float* ib = in + (size_t)b*64*720;
  float acc = 0.f;
  for (int ic=0; ic<64; ic++){
    const float* ip = ib + ic*720;
    const float* wp = ws + ic*9;
    #pragma unroll
    for (int dy=0; dy<3; dy++){
      int iy = oy-1+dy; if ((unsigned)iy >= 20u) continue;
      #pragma unroll
      for (int dx=0; dx<3; dx++){
        int ix = ox-1+dx; if ((unsigned)ix >= 36u) continue;
        acc += ip[iy*36+ix]*wp[dy*3+dx];
      }
    }
  }
  out[(size_t)(b*64+oc)*720 + pos] = fmaxf(acc, 0.f);
}

__global__ __launch_bounds__(TPB) void posadd_kernel(const float* __restrict__ p2,
    const float* __restrict__ pos, float* __restrict__ t){
  int gid = blockIdx.x*TPB + threadIdx.x;
  int d = gid & 63; int n = (gid >> 6) % 180; int b = gid / (180*64);
  t[gid] = p2[(size_t)(b*64+d)*180 + n] + pos[n*64+d];
}

// ---------------- weight transpose+cvt: src[l][R][C] f32 -> dst[l][C][R] bf16
__global__ __launch_bounds__(TPB) void tcvt_kernel(const float* __restrict__ src,
    u16* __restrict__ dst, int R, int C, int total){
  int gid = blockIdx.x*TPB + threadIdx.x;
  if (gid >= total) return;
  int rc = R*C;
  int l = gid / rc; int rem = gid - l*rc; int c = rem / R; int r = rem - c*R;
  dst[gid] = f2b(src[(size_t)l*rc + (size_t)r*C + c]);
}

// pc_w [256][64*9] (k=ic*9+r9) -> wpc [256][r9*64+ic] bf16
__global__ __launch_bounds__(TPB) void tcvt_pc(const float* __restrict__ src,
    u16* __restrict__ dst){
  int gid = blockIdx.x*TPB + threadIdx.x;   // 147456
  if (gid >= 147456) return;
  int oc = gid / 576, k = gid - oc*576;
  int r9 = k >> 6, ic = k & 63;
  dst[gid] = f2b(src[oc*576 + ic*9 + r9]);
}

// caps_w [1024][8][48] -> cwT [1024][48][8] f32
__global__ __launch_bounds__(TPB) void tcvt_cw(const float* __restrict__ src,
    float* __restrict__ dst){
  int gid = blockIdx.x*TPB + threadIdx.x;   // 393216
  if (gid >= 393216) return;
  int i = gid / 384, rem = gid - i*384;
  int o = rem >> 3, e = rem & 7;
  dst[gid] = src[i*384 + e*48 + o];
}

// ---------------- LayerNorm (dim 64) -> bf16 H (used once before the loop)
__global__ __launch_bounds__(TPB) void ln_kernel(const float* __restrict__ x,
    const float* __restrict__ g, const float* __restrict__ bta, u16* __restrict__ out){
  int row = blockIdx.x*4 + (threadIdx.x>>6);
  int lane = threadIdx.x & 63;
  float v = x[(size_t)row*64 + lane];
  float s = v;
  #pragma unroll
  for (int off=32; off; off>>=1) s += __shfl_xor(s, off);
  float mean = s * (1.f/64.f);
  float d = v - mean;
  float q = d*d;
  #pragma unroll
  for (int off=32; off; off>>=1) q += __shfl_xor(q, off);
  float r = rsqrtf(q*(1.f/64.f) + 1e-5f);
  out[(size_t)row*64 + lane] = f2b(d*r*g[lane] + bta[lane]);
}

// ---------------- fused QKV-proj + attention: one block per (head, sample)
__global__ __launch_bounds__(TPB) void attn_fused(const u16* __restrict__ Hg,
    const u16* __restrict__ W, u16* __restrict__ Og){
  __shared__ u16 Kl[192][66];
  __shared__ u16 VT[64][200];
  __shared__ u16 Pw[4][16][104];
  int h = blockIdx.x, s = blockIdx.y;
  int tid = threadIdx.x, wave = tid>>6, lane = tid&63;
  int q = lane>>4, li = lane&15;
  const u16* Hb = Hg + (size_t)s*180*64;
  const u16* Wq = W + (size_t)(h*64)*64;
  const u16* Wk = W + (size_t)(768 + h*64)*64;
  const u16* Wv = W + (size_t)(1536 + h*64)*64;
  for (int p = wave; p < 12; p += 4){
    int m0 = p*16;
    int ar = m0 + li; if (ar > 179) ar = 179;
    const u16* hrow = Hb + (size_t)ar*64 + q*8;
    bf16x8 a0 = *(const bf16x8*)hrow;
    bf16x8 a1 = *(const bf16x8*)(hrow+32);
    #pragma unroll
    for (int nt=0; nt<4; nt++){
      const u16* kr = Wk + (size_t)(nt*16+li)*64 + q*8;
      bf16x8 b0 = *(const bf16x8*)kr;
      bf16x8 b1 = *(const bf16x8*)(kr+32);
      f32x4 ck = {0.f,0.f,0.f,0.f};
      ck = mfma16(a0,b0,ck); ck = mfma16(a1,b1,ck);
      #pragma unroll
      for (int r=0;r<4;r++) Kl[m0+q*4+r][nt*16+li] = f2b(ck[r]);
      const u16* vr = Wv + (size_t)(nt*16+li)*64 + q*8;
      bf16x8 d0 = *(const bf16x8*)vr;
      bf16x8 d1 = *(const bf16x8*)(vr+32);
      f32x4 cv = {0.f,0.f,0.f,0.f};
      cv = mfma16(a0,d0,cv); cv = mfma16(a1,d1,cv);
      #pragma unroll
      for (int r=0;r<4;r++) VT[nt*16+li][m0+q*4+r] = f2b(cv[r]);
    }
  }
  __syncthreads();
  for (int p = wave; p < 12; p += 4){
    int m0 = p*16;
    int ar = m0 + li; if (ar > 179) ar = 179;
    const u16* hrow = Hb + (size_t)ar*64 + q*8;
    bf16x8 a0 = *(const bf16x8*)hrow;
    bf16x8 a1 = *(const bf16x8*)(hrow+32);
    #pragma unroll
    for (int nt=0; nt<4; nt++){
      const u16* qr = Wq + (size_t)(nt*16+li)*64 + q*8;
      bf16x8 b0 = *(const bf16x8*)qr;
      bf16x8 b1 = *(const bf16x8*)(qr+32);
      f32x4 c = {0.f,0.f,0.f,0.f};
      c = mfma16(a0,b0,c); c = mfma16(a1,b1,c);
      #pragma unroll
      for (int r=0;r<4;r++) Pw[wave][q*4+r][nt*16+li] = f2b(c[r]*0.125f);
    }
    bf16x8 qa0 = *(const bf16x8*)&Pw[wave][li][q*8];
    bf16x8 qa1 = *(const bf16x8*)&Pw[wave][li][32+q*8];
    f32x4 S[12];
    #pragma unroll
    for (int t=0;t<12;t++){
      bf16x8 b0 = *(const bf16x8*)&Kl[t*16+li][q*8];
      bf16x8 b1 = *(const bf16x8*)&Kl[t*16+li][32+q*8];
      f32x4 c = {0.f,0.f,0.f,0.f};
      c = mfma16(qa0,b0,c); c = mfma16(qa1,b1,c);
      S[t] = c;
    }
    if (li >= 4){ S[11][0]=-1e30f; S[11][1]=-1e30f; S[11][2]=-1e30f; S[11][3]=-1e30f; }
    float eB[4][6];
    #pragma unroll
    for (int r=0;r<4;r++){
      float mx = S[0][r];
      #pragma unroll
      for (int t=1;t<12;t++) mx = fmaxf(mx, S[t][r]);
      #pragma unroll
      for (int off=8; off; off>>=1) mx = fmaxf(mx, __shfl_xor(mx, off));
      float e[12]; float sum = 0.f;
      #pragma unroll
      for (int t=0;t<12;t++){ e[t] = __expf(S[t][r]-mx); sum += e[t]; }
      #pragma unroll
      for (int off=8; off; off>>=1) sum += __shfl_xor(sum, off);
      float inv = 1.f/sum;
      #pragma unroll
      for (int t=0;t<6;t++) Pw[wave][q*4+r][t*16+li] = f2b(e[t]*inv);
      #pragma unroll
      for (int t=0;t<6;t++) eB[r][t] = e[6+t]*inv;
    }
    f32x4 c4[4];
    #pragma unroll
    for (int nd=0;nd<4;nd++) c4[nd] = (f32x4){0.f,0.f,0.f,0.f};
    {
      bf16x8 pa[3];
      #pragma unroll
      for (int kb=0;kb<3;kb++) pa[kb] = *(const bf16x8*)&Pw[wave][li][kb*32+q*8];
      #pragma unroll
      for (int nd=0;nd<4;nd++){
        #pragma unroll
        for (int kb=0;kb<3;kb++){
          bf16x8 b = *(const bf16x8*)&VT[nd*16+li][kb*32+q*8];
          c4[nd] = mfma16(pa[kb], b, c4[nd]);
        }
      }
    }
    #pragma unroll
    for (int r=0;r<4;r++){
      #pragma unroll
      for (int t=0;t<6;t++) Pw[wave][q*4+r][t*16+li] = f2b(eB[r][t]);
    }
    {
      bf16x8 pa[3];
      #pragma unroll
      for (int kb=0;kb<3;kb++) pa[kb] = *(const bf16x8*)&Pw[wave][li][kb*32+q*8];
      #pragma unroll
      for (int nd=0;nd<4;nd++){
        #pragma unroll
        for (int kb=0;kb<3;kb++){
          bf16x8 b = *(const bf16x8*)&VT[nd*16+li][96+kb*32+q*8];
          c4[nd] = mfma16(pa[kb], b, c4[nd]);
        }
      }
    }
    #pragma unroll
    for (int nd=0; nd<4; nd++){
      #pragma unroll
      for (int r=0;r<4;r++){
        int row = m0 + q*4 + r;
        if (row < 180)
          Og[(size_t)(s*180+row)*768 + h*64 + nd*16 + li] = f2b(c4[nd][r]);
      }
    }
  }
}

// ---------------- out-proj + residual + fused LN2 -> Hg
__global__ __launch_bounds__(TPB) void gemm_outp(const u16* __restrict__ Og,
    const u16* __restrict__ WOT, const float* __restrict__ outb,
    const float* __restrict__ lng, const float* __restrict__ lnb,
    float* __restrict__ t, u16* __restrict__ HgOut){
  int wave = threadIdx.x>>6, lane = threadIdx.x&63, q = lane>>4, li = lane&15;
  int m0 = blockIdx.x*64 + wave*16;
  f32x4 acc[4];
  #pragma unroll
  for (int nd=0;nd<4;nd++) acc[nd] = (f32x4){0.f,0.f,0.f,0.f};
  for (int kb=0; kb<24; kb++){
    bf16x8 a = *(const bf16x8*)(Og + (size_t)(m0+li)*768 + kb*32 + q*8);
    #pragma unroll
    for (int nd=0;nd<4;nd++){
      bf16x8 b = *(const bf16x8*)(WOT + (size_t)(nd*16+li)*768 + kb*32 + q*8);
      acc[nd] = mfma16(a, b, acc[nd]);
    }
  }
  float tv[4][4]; float gv[4], bvn[4];
  #pragma unroll
  for (int nd=0;nd<4;nd++){
    int col = nd*16 + li;
    float bv = outb[col];
    gv[nd] = lng[col]; bvn[nd] = lnb[col];
    #pragma unroll
    for (int r=0;r<4;r++){
      size_t off = (size_t)(m0 + q*4 + r)*64 + col;
      float v = t[off] + acc[nd][r] + bv;
      t[off] = v;
      tv[nd][r] = v;
    }
  }
  #pragma unroll
  for (int r=0;r<4;r++){
    float s = tv[0][r]+tv[1][r]+tv[2][r]+tv[3][r];
    #pragma unroll
    for (int off=8; off; off>>=1) s += __shfl_xor(s, off);
    float mean = s*(1.f/64.f);
    float qs = 0.f;
    #pragma unroll
    for (int nd=0;nd<4;nd++){ float d = tv[nd][r]-mean; qs += d*d; }
    #pragma unroll
    for (int off=8; off; off>>=1) qs += __shfl_xor(qs, off);
    float rinv = rsqrtf(qs*(1.f/64.f) + 1e-5f);
    size_t rowoff = (size_t)(m0 + q*4 + r)*64;
    #pragma unroll
    for (int nd=0;nd<4;nd++){
      int col = nd*16 + li;
      HgOut[rowoff + col] = f2b((tv[nd][r]-mean)*rinv*gv[nd] + bvn[nd]);
    }
  }
}

// ---------------- fused ffn: G=gelu(Hg@W1^T+b1) (LDS panel) -> t+=G@W2^T+b2 -> LN(next) -> Hg
__global__ __launch_bounds__(TPB) void gemm_ffn(const u16* __restrict__ Hg,
    const u16* __restrict__ W1, const float* __restrict__ b1,
    const u16* __restrict__ W2, const float* __restrict__ b2,
    const float* __restrict__ lng, const float* __restrict__ lnb,
    float* __restrict__ t, u16* __restrict__ HgOut){
  __shared__ u16 panel[4][16][264];
  int wave = threadIdx.x>>6, lane = threadIdx.x&63, q = lane>>4, li = lane&15;
  int m0 = blockIdx.x*64 + wave*16;
  const u16* arow = Hg + (size_t)(m0+li)*64 + q*8;
  bf16x8 a0 = *(const bf16x8*)arow;
  bf16x8 a1 = *(const bf16x8*)(arow + 32);
  for (int nt=0; nt<16; nt++){
    const u16* brow = W1 + (size_t)(nt*16+li)*64 + q*8;
    bf16x8 b0 = *(const bf16x8*)brow;
    bf16x8 b1v = *(const bf16x8*)(brow + 32);
    f32x4 c = {0.f,0.f,0.f,0.f};
    c = mfma16(a0, b0, c);
    c = mfma16(a1, b1v, c);
    int col = nt*16 + li;
    float bv = b1[col];
    #pragma unroll
    for (int r=0;r<4;r++){
      float v = c[r] + bv;
      v = v*0.5f*(1.f + erff(v*0.70710678118f));
      panel[wave][q*4+r][col] = f2b(v);
    }
  }
  // wave-private panel: in-wave RAW, no barrier needed
  bf16x8 ap[8];
  #pragma unroll
  for (int kb=0;kb<8;kb++) ap[kb] = *(const bf16x8*)&panel[wave][li][kb*32 + q*8];
  f32x4 acc[4];
  #pragma unroll
  for (int nd=0;nd<4;nd++) acc[nd] = (f32x4){0.f,0.f,0.f,0.f};
  #pragma unroll
  for (int kb=0; kb<8; kb++){
    #pragma unroll
    for (int nd=0;nd<4;nd++){
      bf16x8 b = *(const bf16x8*)(W2 + (size_t)(nd*16+li)*256 + kb*32 + q*8);
      acc[nd] = mfma16(ap[kb], b, acc[nd]);
    }
  }
  float tv[4][4]; float gv[4], bvn[4];
  #pragma unroll
  for (int nd=0;nd<4;nd++){
    int col = nd*16 + li;
    float bv = b2[col];
    gv[nd] = lng[col]; bvn[nd] = lnb[col];
    #pragma unroll
    for (int r=0;r<4;r++){
      size_t off = (size_t)(m0 + q*4 + r)*64 + col;
      float v = t[off] + acc[nd][r] + bv;
      t[off] = v;
      tv[nd][r] = v;
    }
  }
  #pragma unroll
  for (int r=0;r<4;r++){
    float s = tv[0][r]+tv[1][r]+tv[2][r]+tv[3][r];
    #pragma unroll
    for (int off=8; off; off>>=1) s += __shfl_xor(s, off);
    float mean = s*(1.f/64.f);
    float qs = 0.f;
    #pragma unroll
    for (int nd=0;nd<4;nd++){ float d = tv[nd][r]-mean; qs += d*d; }
    #pragma unroll
    for (int off=8; off; off>>=1) qs += __shfl_xor(qs, off);
    float rinv = rsqrtf(qs*(1.f/64.f) + 1e-5f);
    size_t rowoff = (size_t)(m0 + q*4 + r)*64;
    #pragma unroll
    for (int nd=0;nd<4;nd++){
      int col = nd*16 + li;
      HgOut[rowoff + col] = f2b((tv[nd][r]-mean)*rinv*gv[nd] + bvn[nd]);
    }
  }
}

// ---------------- PrimaryCaps via MFMA + fused squash: one block per sample
// A: patches from t (k = r9*64+ic, contiguous ic-8); B: wpc [256][576]; M=32, N=256, K=576
__global__ __launch_bounds__(TPB) void pcaps_mfma(const float* __restrict__ t,
    const u16* __restrict__ wpc, const float* __restrict__ bias, float* __restrict__ caps){
  int b = blockIdx.x;
  int wave = threadIdx.x>>6, lane = threadIdx.x&63, q = lane>>4, li = lane&15;
  int mt = wave & 1, nh = wave >> 1;
  const float* tb = t + (size_t)b*180*64;
  int pos_a = mt*16 + li;               // A-operand row
  int oy_a = pos_a >> 3, ox_a = pos_a & 7;
  f32x4 acc[8];
  #pragma unroll
  for (int nt=0;nt<8;nt++) acc[nt] = (f32x4){0.f,0.f,0.f,0.f};
  for (int ks=0; ks<18; ks++){
    int k0 = ks*32 + q*8;
    int r9 = k0 >> 6, ic = k0 & 63;
    int dy = r9/3, dx = r9 - 3*dy;
    const float* src = tb + ((2*oy_a+dy)*18 + (2*ox_a+dx))*64 + ic;
    float4 f0 = *(const float4*)src;
    float4 f1 = *(const float4*)(src+4);
    bf16x8 a;
    a[0]=(short)f2b(f0.x); a[1]=(short)f2b(f0.y); a[2]=(short)f2b(f0.z); a[3]=(short)f2b(f0.w);
    a[4]=(short)f2b(f1.x); a[5]=(short)f2b(f1.y); a[6]=(short)f2b(f1.z); a[7]=(short)f2b(f1.w);
    #pragma unroll
    for (int nt=0;nt<8;nt++){
      bf16x8 bb8 = *(const bf16x8*)(wpc + (size_t)(nh*128 + nt*16 + li)*576 + k0);
      acc[nt] = mfma16(a, bb8, acc[nt]);
    }
  }
  #pragma unroll
  for (int nt=0;nt<8;nt++){
    int oc = nh*128 + nt*16 + li;
    float bv = bias[oc];
    #pragma unroll
    for (int r=0;r<4;r++){
      int prow = mt*16 + q*4 + r;
      float val = acc[nt][r] + bv;
      float l2 = val*val;
      l2 += __shfl_xor(l2, 1);
      l2 += __shfl_xor(l2, 2);
      l2 += __shfl_xor(l2, 4);
      float sc = (l2 > 0.f) ? l2/((1.f+l2)*sqrtf(l2)) : 0.f;
      caps[((size_t)b*1024 + (oc>>3)*32 + prow)*8 + (oc&7)] = val*sc;
    }
  }
}

// ---------------- u[b,i,o] = caps[b,i,:] . cwT[i,o,:]
__global__ __launch_bounds__(TPB) void u_kernel(const float* __restrict__ caps,
    const float* __restrict__ cwT, float* __restrict__ u){
  int gid = blockIdx.x*TPB + threadIdx.x;
  int o = gid % 48; int i = (gid/48) & 1023; int b = gid/(48*1024);
  const float* cp = caps + ((size_t)b*1024 + i)*8;
  const float* wp = cwT + ((size_t)i*48 + o)*8;
  float4 c0 = *(const float4*)cp, c1 = *(const float4*)(cp+4);
  float4 w0 = *(const float4*)wp, w1 = *(const float4*)(wp+4);
  u[gid] = c0.x*w0.x + c0.y*w0.y + c0.z*w0.z + c0.w*w0.w
         + c1.x*w1.x + c1.y*w1.y + c1.z*w1.z + c1.w*w1.w;
}

__global__ __launch_bounds__(TPB) void routing_kernel(const float* __restrict__ u,
    const float* __restrict__ b_route, float* __restrict__ out){
  __shared__ float bb[3072];
  __shared__ float vsh[48];
  __shared__ float red[4][48];
  __shared__ float ssh[48];
  int b = blockIdx.x, tid = threadIdx.x;
  const float* ub = u + (size_t)b*49152;
  for (int idx=tid; idx<3072; idx+=TPB) bb[idx] = b_route[idx];
  __syncthreads();
  for (int it=0; it<4; it++){
    if (it > 0){
      for (int idx=tid; idx<3072; idx+=TPB){
        int i = idx/3, j = idx - i*3;
        const float* up = ub + i*48 + j*16;
        float s = 0.f;
        #pragma unroll
        for (int e=0;e<16;e++) s += up[e]*vsh[j*16+e];
        bb[idx] += s;
      }
      __syncthreads();
    }
    float acc[48];
    #pragma unroll
    for (int q2=0;q2<48;q2++) acc[q2] = 0.f;
    for (int i=tid; i<1024; i+=TPB){
      float b0=bb[i*3], b1=bb[i*3+1], b2v=bb[i*3+2];
      float m = fmaxf(b0, fmaxf(b1, b2v));
      float e0=__expf(b0-m), e1=__expf(b1-m), e2=__expf(b2v-m);
      float inv = 1.f/(e0+e1+e2);
      float c0=e0*inv, c1=e1*inv, c2=e2*inv;
      const float* up = ub + i*48;
      #pragma unroll
      for (int e=0;e<16;e++){
        acc[e]    += c0*up[e];
        acc[16+e] += c1*up[16+e];
        acc[32+e] += c2*up[32+e];
      }
    }
    #pragma unroll
    for (int q2=0;q2<48;q2++){
      float v = acc[q2];
      #pragma unroll
      for (int off=32; off; off>>=1) v += __shfl_xor(v, off);
      if ((tid&63)==0) red[tid>>6][q2] = v;
    }
    __syncthreads();
    if (tid < 48) ssh[tid] = red[0][tid]+red[1][tid]+red[2][tid]+red[3][tid];
    __syncthreads();
    if (tid < 48){
      int j = tid >> 4;
      float l2 = 0.f;
      #pragma unroll
      for (int e=0;e<16;e++) l2 += ssh[j*16+e]*ssh[j*16+e];
      float sc = (l2 > 0.f) ? l2/((1.f+l2)*sqrtf(l2)) : 0.f;
      vsh[tid] = ssh[tid]*sc;
    }
    __syncthreads();
  }
  if (tid < 3){
    float l2 = 0.f;
    #pragma unroll
    for (int e=0;e<16;e++) l2 += vsh[tid*16+e]*vsh[tid*16+e];
    out[b*3+tid] = sqrtf(l2);
  }
}

extern "C" void kernel_launch(void* const* d_in, const int* in_sizes, int n_in,
                              void* d_out, int out_size, void* d_ws, size_t ws_size,
                              hipStream_t stream){
  const float* x       = (const float*)d_in[0];
  const float* conv1_w = (const float*)d_in[1];
  const float* conv2_w = (const float*)d_in[2];
  const float* pos_emb = (const float*)d_in[3];
  const float* ln1_g   = (const float*)d_in[4];
  const float* ln1_b   = (const float*)d_in[5];
  const float* qkv_w   = (const float*)d_in[6];
  const float* out_w   = (const float*)d_in[7];
  const float* out_b   = (const float*)d_in[8];
  const float* ln2_g   = (const float*)d_in[9];
  const float* ln2_b   = (const float*)d_in[10];
  const float* ff1_w   = (const float*)d_in[11];
  const float* ff1_b   = (const float*)d_in[12];
  const float* ff2_w   = (const float*)d_in[13];
  const float* ff2_b   = (const float*)d_in[14];
  const float* pc_w    = (const float*)d_in[15];
  const float* pc_b    = (const float*)d_in[16];
  const float* caps_w  = (const float*)d_in[17];
  const float* b_route = (const float*)d_in[18];
  float* out = (float*)d_out;

  // ---- workspace: peak 95,846,400 B (< 97.3 MB proven safe) ----
  char* ws = (char*)d_ws;
  float* t_buf = (float*)(ws);                  // [46080,64] f32   0 .. 11,796,480
  u16*  Hg    = (u16*)(ws + 11796480);          // [46080,64] bf16  .. 17,694,720
  u16*  WQKVT = (u16*)(ws + 17694720);          // [12][2304][64]   .. 21,233,664
  u16*  WOT   = (u16*)(ws + 21233664);          // [12][64][768]    .. 22,413,312
  u16*  WF1T  = (u16*)(ws + 22413312);          // [12][256][64]    .. 22,806,528
  u16*  WF2T  = (u16*)(ws + 22806528);          // [12][64][256]    .. 23,199,744
  u16*  wpc   = (u16*)(ws + 23199744);          // [256][576] bf16  .. 23,494,656
  float* cwT  = (float*)(ws + 23494656);        // [1024][48][8]    .. 25,067,520
  char* win   = ws + 25067520;                  // 70,778,880 B window .. 95,846,400
  u16*  Og    = (u16*)win;                      // [46080][768] bf16
  float* c1out = (float*)(win);                 // 47,185,920
  float* p1out = (float*)(win + 47185920);      // 11,796,480
  float* c2out = (float*)(win + 58982400);      // 11,796,480
  float* p2out = (float*)(win + 47185920);      //  2,949,120 (p1out dead by then)
  float* caps  = (float*)(win);                 //  8,388,608
  float* u_buf = (float*)(win + 8388608);       // 50,331,648

  // ---- conv-embed (4 chunks of 64 samples) ----
  for (int c = 0; c < 4; c++){
    const float* xc = x + (size_t)c*64*3*40*72;
    conv1_kernel<<<46080, TPB, 0, stream>>>(xc, conv1_w, c1out);
    maxpool_kernel<<<11520, TPB, 0, stream>>>(c1out, p1out, 40,72,20,36, 2949120);
    conv2_kernel<<<12288, TPB, 0, stream>>>(p1out, conv2_w, c2out);
    maxpool_kernel<<<2880, TPB, 0, stream>>>(c2out, p2out, 20,36,10,18, 737280);
    posadd_kernel<<<2880, TPB, 0, stream>>>(p2out, pos_emb, t_buf + (size_t)c*11520*64);
  }

  // ---- weight prep ----
  tcvt_kernel<<<6912, TPB, 0, stream>>>(qkv_w, WQKVT, 64, 2304, 12*64*2304);
  tcvt_kernel<<<2304, TPB, 0, stream>>>(out_w, WOT, 768, 64, 12*768*64);
  tcvt_kernel<<<768, TPB, 0, stream>>>(ff1_w, WF1T, 64, 256, 12*64*256);
  tcvt_kernel<<<768, TPB, 0, stream>>>(ff2_w, WF2T, 256, 64, 12*256*64);
  tcvt_pc<<<576, TPB, 0, stream>>>(pc_w, wpc);
  tcvt_cw<<<1536, TPB, 0, stream>>>(caps_w, cwT);

  // ---- transformer: initial LN1, then 24 x {attn, outp(+LN2), ffn(+LN1-next)} ----
  ln_kernel<<<11520, TPB, 0, stream>>>(t_buf, ln1_g, ln1_b, Hg);
  for (int itr=0; itr<24; itr++){
    int l = itr % 12;
    int ln = (itr+1) % 12;   // ln1 params for next application
    attn_fused<<<dim3(12,256), TPB, 0, stream>>>(Hg, WQKVT + (size_t)l*2304*64, Og);
    gemm_outp<<<720, TPB, 0, stream>>>(Og, WOT + (size_t)l*64*768, out_b + l*64,
                                       ln2_g + l*64, ln2_b + l*64, t_buf, Hg);
    gemm_ffn<<<720, TPB, 0, stream>>>(Hg, WF1T + (size_t)l*256*64, ff1_b + l*256,
                                      WF2T + (size_t)l*64*256, ff2_b + l*64,
                                      ln1_g + ln*64, ln1_b + ln*64, t_buf, Hg);
  }

  // ---- capsule head ----
  pcaps_mfma<<<256, TPB, 0, stream>>>(t_buf, wpc, pc_b, caps);
  u_kernel<<<49152, TPB, 0, stream>>>(caps, cwT, u_buf);
  routing_kernel<<<256, TPB, 0, stream>>>(u_buf, b_route, out);
}

// Round 8
// 5662.994 us; speedup vs baseline: 9.6254x; 1.3393x over previous
//
#include <hip/hip_runtime.h>
#include <hip/hip_bf16.h>
#include <math.h>

#define TPB 256
typedef unsigned short u16;
typedef __attribute__((ext_vector_type(8))) short bf16x8;
typedef __attribute__((ext_vector_type(4))) float f32x4;

__device__ __forceinline__ float b2f(u16 u){ return __uint_as_float(((unsigned)u)<<16); }
__device__ __forceinline__ u16 f2b(float f){
  unsigned x = __float_as_uint(f);
  unsigned r = (x + 0x7fffu + ((x>>16)&1u)) >> 16;
  return (u16)r;
}
__device__ __forceinline__ f32x4 mfma16(bf16x8 a, bf16x8 b, f32x4 c){
  return __builtin_amdgcn_mfma_f32_16x16x32_bf16(a, b, c, 0, 0, 0);
}

// ---------------- Conv1 (per 64-sample chunk) -> NHWC bf16 [64][40][72][64]
// oc = lane; weights LDS-staged; pixel reads wave-uniform (scalar); stores coalesced.
__global__ __launch_bounds__(TPB) void conv1_kernel(const float* __restrict__ x,
    const float* __restrict__ w, u16* __restrict__ out){
  __shared__ float wsh[27][64];
  int tid = threadIdx.x;
  for (int idx = tid; idx < 1728; idx += TPB){
    int oc = idx / 27, i = idx - oc*27;
    wsh[i][oc] = w[idx];
  }
  __syncthreads();
  int pos = blockIdx.x*4 + (tid>>6);          // chunk-local (b*2880 + p)
  int oc = tid & 63;
  int b = pos / 2880; int p = pos - b*2880;
  int oy = p / 72, ox = p - (p/72)*72;
  const float* xb = x + (size_t)b*3*2880;
  float acc = 0.f;
  #pragma unroll
  for (int dy=0; dy<3; dy++){
    int iy = oy-1+dy; if ((unsigned)iy >= 40u) continue;
    #pragma unroll
    for (int dx=0; dx<3; dx++){
      int ix = ox-1+dx; if ((unsigned)ix >= 72u) continue;
      #pragma unroll
      for (int ic=0; ic<3; ic++)
        acc += xb[ic*2880 + iy*72+ix] * wsh[(ic*3+dy)*3+dx][oc];
    }
  }
  out[(size_t)pos*64 + oc] = f2b(fmaxf(acc, 0.f));
}

// ---------------- MaxPool1 3x3 s2 p1 on bf16 NHWC (integer max valid: inputs >= 0)
// in [64][40][72][64] -> out [64][20][36][64]; one thread = 4 channels
__global__ __launch_bounds__(TPB) void maxpool1_kernel(const u16* __restrict__ in,
    u16* __restrict__ out){
  int gid = blockIdx.x*TPB + threadIdx.x;     // 737,280 = 64*720*16
  int c4 = gid & 15; int p = (gid>>4) % 720; int b = gid / 11520;
  int oy = p/36, ox = p - (p/36)*36;
  ushort4 m = make_ushort4(0,0,0,0);
  #pragma unroll
  for (int dy=0; dy<3; dy++){
    int iy = oy*2-1+dy; if ((unsigned)iy >= 40u) continue;
    #pragma unroll
    for (int dx=0; dx<3; dx++){
      int ix = ox*2-1+dx; if ((unsigned)ix >= 72u) continue;
      ushort4 v = *(const ushort4*)(in + ((size_t)b*2880 + iy*72+ix)*64 + c4*4);
      m.x = v.x > m.x ? v.x : m.x;  m.y = v.y > m.y ? v.y : m.y;
      m.z = v.z > m.z ? v.z : m.z;  m.w = v.w > m.w ? v.w : m.w;
    }
  }
  *(ushort4*)(out + ((size_t)b*720 + p)*64 + c4*4) = m;
}

// ---------------- Conv2 via MFMA: per sample GEMM M=720, N=64, K=576 (9 taps x 64 ic)
// p1 NHWC bf16 full batch [256][20][36][64]; wc2 [64][r9*64+ic] bf16; c2 f32 NHWC
__global__ __launch_bounds__(TPB) void conv2_mfma(const u16* __restrict__ p1,
    const u16* __restrict__ wc2, float* __restrict__ c2){
  int s = blockIdx.y;
  int wave = threadIdx.x>>6, lane = threadIdx.x&63, q = lane>>4, li = lane&15;
  int mt = blockIdx.x*4 + wave;
  if (mt >= 45) return;                       // no barriers below
  int m0 = mt*16;
  int pos = m0 + li;
  int oy = pos/36, ox = pos - (pos/36)*36;
  const u16* ps = p1 + (size_t)s*720*64;
  f32x4 acc[4];
  #pragma unroll
  for (int nt=0;nt<4;nt++) acc[nt] = (f32x4){0.f,0.f,0.f,0.f};
  #pragma unroll
  for (int ks=0; ks<18; ks++){
    const int r9 = ks>>1;                     // compile-time per unrolled iter
    const int dy = r9/3, dx = r9 - 3*(r9/3);
    int k0 = ks*32 + q*8;
    int ic8 = (ks&1)*32 + q*8;
    int iy = oy-1+dy, ix = ox-1+dx;
    bf16x8 a;
    if ((unsigned)iy < 20u && (unsigned)ix < 36u)
      a = *(const bf16x8*)(ps + (size_t)(iy*36+ix)*64 + ic8);
    else
      a = (bf16x8){0,0,0,0,0,0,0,0};
    #pragma unroll
    for (int nt=0;nt<4;nt++){
      bf16x8 b = *(const bf16x8*)(wc2 + (size_t)(nt*16+li)*576 + k0);
      acc[nt] = mfma16(a, b, acc[nt]);
    }
  }
  #pragma unroll
  for (int nt=0;nt<4;nt++){
    int oc = nt*16 + li;
    #pragma unroll
    for (int r=0;r<4;r++){
      int prow = m0 + q*4 + r;
      c2[((size_t)s*720 + prow)*64 + oc] = fmaxf(acc[nt][r], 0.f);
    }
  }
}

// ---------------- MaxPool2 + pos_emb fused: c2 f32 NHWC -> t [256][180][64] f32
__global__ __launch_bounds__(TPB) void pool2pos_kernel(const float* __restrict__ c2,
    const float* __restrict__ pos, float* __restrict__ t){
  int gid = blockIdx.x*TPB + threadIdx.x;     // 737,280 = 256*180*16
  int d4 = gid & 15; int n = (gid>>4) % 180; int b = gid / 2880;
  int oy = n/18, ox = n - (n/18)*18;
  float4 m = make_float4(0.f,0.f,0.f,0.f);    // inputs are relu'd >= 0
  #pragma unroll
  for (int dy=0; dy<3; dy++){
    int iy = oy*2-1+dy; if ((unsigned)iy >= 20u) continue;
    #pragma unroll
    for (int dx=0; dx<3; dx++){
      int ix = ox*2-1+dx; if ((unsigned)ix >= 36u) continue;
      float4 v = *(const float4*)(c2 + ((size_t)b*720 + iy*36+ix)*64 + d4*4);
      m.x = fmaxf(m.x, v.x); m.y = fmaxf(m.y, v.y);
      m.z = fmaxf(m.z, v.z); m.w = fmaxf(m.w, v.w);
    }
  }
  float4 pe = *(const float4*)(pos + n*64 + d4*4);
  *(float4*)(t + ((size_t)b*180 + n)*64 + d4*4) =
      make_float4(m.x+pe.x, m.y+pe.y, m.z+pe.z, m.w+pe.w);
}

// ---------------- weight transpose+cvt: src[l][R][C] f32 -> dst[l][C][R] bf16
__global__ __launch_bounds__(TPB) void tcvt_kernel(const float* __restrict__ src,
    u16* __restrict__ dst, int R, int C, int total){
  int gid = blockIdx.x*TPB + threadIdx.x;
  if (gid >= total) return;
  int rc = R*C;
  int l = gid / rc; int rem = gid - l*rc; int c = rem / R; int r = rem - c*R;
  dst[gid] = f2b(src[(size_t)l*rc + (size_t)r*C + c]);
}

// pc_w/conv2_w [OC][64*9] (k=ic*9+r9) -> [OC][r9*64+ic] bf16
__global__ __launch_bounds__(TPB) void tcvt_conv(const float* __restrict__ src,
    u16* __restrict__ dst, int total){
  int gid = blockIdx.x*TPB + threadIdx.x;
  if (gid >= total) return;
  int oc = gid / 576, k = gid - oc*576;
  int r9 = k >> 6, ic = k & 63;
  dst[gid] = f2b(src[oc*576 + ic*9 + r9]);
}

// caps_w [1024][8][48] -> cwT [1024][48][8] f32
__global__ __launch_bounds__(TPB) void tcvt_cw(const float* __restrict__ src,
    float* __restrict__ dst){
  int gid = blockIdx.x*TPB + threadIdx.x;
  if (gid >= 393216) return;
  int i = gid / 384, rem = gid - i*384;
  int o = rem >> 3, e = rem & 7;
  dst[gid] = src[i*384 + e*48 + o];
}

// ---------------- LayerNorm (dim 64) -> bf16 H (once, before the loop)
__global__ __launch_bounds__(TPB) void ln_kernel(const float* __restrict__ x,
    const float* __restrict__ g, const float* __restrict__ bta, u16* __restrict__ out){
  int row = blockIdx.x*4 + (threadIdx.x>>6);
  int lane = threadIdx.x & 63;
  float v = x[(size_t)row*64 + lane];
  float s = v;
  #pragma unroll
  for (int off=32; off; off>>=1) s += __shfl_xor(s, off);
  float mean = s * (1.f/64.f);
  float d = v - mean;
  float q = d*d;
  #pragma unroll
  for (int off=32; off; off>>=1) q += __shfl_xor(q, off);
  float r = rsqrtf(q*(1.f/64.f) + 1e-5f);
  out[(size_t)row*64 + lane] = f2b(d*r*g[lane] + bta[lane]);
}

// ---------------- fused QKV-proj + attention: one block per (head, sample)
__global__ __launch_bounds__(TPB) void attn_fused(const u16* __restrict__ Hg,
    const u16* __restrict__ W, u16* __restrict__ Og){
  __shared__ u16 Kl[192][66];
  __shared__ u16 VT[64][204];
  __shared__ u16 Pw[4][16][104];
  int h = blockIdx.x, s = blockIdx.y;
  int tid = threadIdx.x, wave = tid>>6, lane = tid&63;
  int q = lane>>4, li = lane&15;
  const u16* Hb = Hg + (size_t)s*180*64;
  const u16* Wq = W + (size_t)(h*64)*64;
  const u16* Wk = W + (size_t)(768 + h*64)*64;
  const u16* Wv = W + (size_t)(1536 + h*64)*64;
  for (int p = wave; p < 12; p += 4){
    int m0 = p*16;
    int ar = m0 + li; if (ar > 179) ar = 179;
    const u16* hrow = Hb + (size_t)ar*64 + q*8;
    bf16x8 a0 = *(const bf16x8*)hrow;
    bf16x8 a1 = *(const bf16x8*)(hrow+32);
    #pragma unroll
    for (int nt=0; nt<4; nt++){
      const u16* kr = Wk + (size_t)(nt*16+li)*64 + q*8;
      bf16x8 b0 = *(const bf16x8*)kr;
      bf16x8 b1 = *(const bf16x8*)(kr+32);
      f32x4 ck = {0.f,0.f,0.f,0.f};
      ck = mfma16(a0,b0,ck); ck = mfma16(a1,b1,ck);
      #pragma unroll
      for (int r=0;r<4;r++) Kl[m0+q*4+r][nt*16+li] = f2b(ck[r]);
      const u16* vr = Wv + (size_t)(nt*16+li)*64 + q*8;
      bf16x8 d0 = *(const bf16x8*)vr;
      bf16x8 d1 = *(const bf16x8*)(vr+32);
      f32x4 cv = {0.f,0.f,0.f,0.f};
      cv = mfma16(a0,d0,cv); cv = mfma16(a1,d1,cv);
      #pragma unroll
      for (int r=0;r<4;r++) VT[nt*16+li][m0+q*4+r] = f2b(cv[r]);
    }
  }
  __syncthreads();
  for (int p = wave; p < 12; p += 4){
    int m0 = p*16;
    int ar = m0 + li; if (ar > 179) ar = 179;
    const u16* hrow = Hb + (size_t)ar*64 + q*8;
    bf16x8 a0 = *(const bf16x8*)hrow;
    bf16x8 a1 = *(const bf16x8*)(hrow+32);
    #pragma unroll
    for (int nt=0; nt<4; nt++){
      const u16* qr = Wq + (size_t)(nt*16+li)*64 + q*8;
      bf16x8 b0 = *(const bf16x8*)qr;
      bf16x8 b1 = *(const bf16x8*)(qr+32);
      f32x4 c = {0.f,0.f,0.f,0.f};
      c = mfma16(a0,b0,c); c = mfma16(a1,b1,c);
      #pragma unroll
      for (int r=0;r<4;r++) Pw[wave][q*4+r][nt*16+li] = f2b(c[r]*0.125f);
    }
    bf16x8 qa0 = *(const bf16x8*)&Pw[wave][li][q*8];
    bf16x8 qa1 = *(const bf16x8*)&Pw[wave][li][32+q*8];
    f32x4 S[12];
    #pragma unroll
    for (int t=0;t<12;t++){
      bf16x8 b0 = *(const bf16x8*)&Kl[t*16+li][q*8];
      bf16x8 b1 = *(const bf16x8*)&Kl[t*16+li][32+q*8];
      f32x4 c = {0.f,0.f,0.f,0.f};
      c = mfma16(qa0,b0,c); c = mfma16(qa1,b1,c);
      S[t] = c;
    }
    if (li >= 4){ S[11][0]=-1e30f; S[11][1]=-1e30f; S[11][2]=-1e30f; S[11][3]=-1e30f; }
    float eB[4][6];
    #pragma unroll
    for (int r=0;r<4;r++){
      float mx = S[0][r];
      #pragma unroll
      for (int t=1;t<12;t++) mx = fmaxf(mx, S[t][r]);
      #pragma unroll
      for (int off=8; off; off>>=1) mx = fmaxf(mx, __shfl_xor(mx, off));
      float e[12]; float sum = 0.f;
      #pragma unroll
      for (int t=0;t<12;t++){ e[t] = __expf(S[t][r]-mx); sum += e[t]; }
      #pragma unroll
      for (int off=8; off; off>>=1) sum += __shfl_xor(sum, off);
      float inv = 1.f/sum;
      #pragma unroll
      for (int t=0;t<6;t++) Pw[wave][q*4+r][t*16+li] = f2b(e[t]*inv);
      #pragma unroll
      for (int t=0;t<6;t++) eB[r][t] = e[6+t]*inv;
    }
    f32x4 c4[4];
    #pragma unroll
    for (int nd=0;nd<4;nd++) c4[nd] = (f32x4){0.f,0.f,0.f,0.f};
    {
      bf16x8 pa[3];
      #pragma unroll
      for (int kb=0;kb<3;kb++) pa[kb] = *(const bf16x8*)&Pw[wave][li][kb*32+q*8];
      #pragma unroll
      for (int nd=0;nd<4;nd++){
        #pragma unroll
        for (int kb=0;kb<3;kb++){
          bf16x8 b = *(const bf16x8*)&VT[nd*16+li][kb*32+q*8];
          c4[nd] = mfma16(pa[kb], b, c4[nd]);
        }
      }
    }
    #pragma unroll
    for (int r=0;r<4;r++){
      #pragma unroll
      for (int t=0;t<6;t++) Pw[wave][q*4+r][t*16+li] = f2b(eB[r][t]);
    }
    {
      bf16x8 pa[3];
      #pragma unroll
      for (int kb=0;kb<3;kb++) pa[kb] = *(const bf16x8*)&Pw[wave][li][kb*32+q*8];
      #pragma unroll
      for (int nd=0;nd<4;nd++){
        #pragma unroll
        for (int kb=0;kb<3;kb++){
          bf16x8 b = *(const bf16x8*)&VT[nd*16+li][96+kb*32+q*8];
          c4[nd] = mfma16(pa[kb], b, c4[nd]);
        }
      }
    }
    #pragma unroll
    for (int nd=0; nd<4; nd++){
      #pragma unroll
      for (int r=0;r<4;r++){
        int row = m0 + q*4 + r;
        if (row < 180)
          Og[(size_t)(s*180+row)*768 + h*64 + nd*16 + li] = f2b(c4[nd][r]);
      }
    }
  }
}

// ---------------- out-proj + residual + fused LN2 -> Hg
__global__ __launch_bounds__(TPB) void gemm_outp(const u16* __restrict__ Og,
    const u16* __restrict__ WOT, const float* __restrict__ outb,
    const float* __restrict__ lng, const float* __restrict__ lnb,
    float* __restrict__ t, u16* __restrict__ HgOut){
  int wave = threadIdx.x>>6, lane = threadIdx.x&63, q = lane>>4, li = lane&15;
  int m0 = blockIdx.x*64 + wave*16;
  f32x4 acc[4];
  #pragma unroll
  for (int nd=0;nd<4;nd++) acc[nd] = (f32x4){0.f,0.f,0.f,0.f};
  for (int kb=0; kb<24; kb++){
    bf16x8 a = *(const bf16x8*)(Og + (size_t)(m0+li)*768 + kb*32 + q*8);
    #pragma unroll
    for (int nd=0;nd<4;nd++){
      bf16x8 b = *(const bf16x8*)(WOT + (size_t)(nd*16+li)*768 + kb*32 + q*8);
      acc[nd] = mfma16(a, b, acc[nd]);
    }
  }
  float tv[4][4]; float gv[4], bvn[4];
  #pragma unroll
  for (int nd=0;nd<4;nd++){
    int col = nd*16 + li;
    float bv = outb[col];
    gv[nd] = lng[col]; bvn[nd] = lnb[col];
    #pragma unroll
    for (int r=0;r<4;r++){
      size_t off = (size_t)(m0 + q*4 + r)*64 + col;
      float v = t[off] + acc[nd][r] + bv;
      t[off] = v;
      tv[nd][r] = v;
    }
  }
  #pragma unroll
  for (int r=0;r<4;r++){
    float s = tv[0][r]+tv[1][r]+tv[2][r]+tv[3][r];
    #pragma unroll
    for (int off=8; off; off>>=1) s += __shfl_xor(s, off);
    float mean = s*(1.f/64.f);
    float qs = 0.f;
    #pragma unroll
    for (int nd=0;nd<4;nd++){ float d = tv[nd][r]-mean; qs += d*d; }
    #pragma unroll
    for (int off=8; off; off>>=1) qs += __shfl_xor(qs, off);
    float rinv = rsqrtf(qs*(1.f/64.f) + 1e-5f);
    size_t rowoff = (size_t)(m0 + q*4 + r)*64;
    #pragma unroll
    for (int nd=0;nd<4;nd++){
      int col = nd*16 + li;
      HgOut[rowoff + col] = f2b((tv[nd][r]-mean)*rinv*gv[nd] + bvn[nd]);
    }
  }
}

// ---------------- fused ffn: gelu(Hg@W1^T+b1) -> LDS panel -> t+=@W2^T+b2 -> LN(next) -> Hg
__global__ __launch_bounds__(TPB) void gemm_ffn(const u16* __restrict__ Hg,
    const u16* __restrict__ W1, const float* __restrict__ b1,
    const u16* __restrict__ W2, const float* __restrict__ b2,
    const float* __restrict__ lng, const float* __restrict__ lnb,
    float* __restrict__ t, u16* __restrict__ HgOut){
  __shared__ u16 panel[4][16][264];
  int wave = threadIdx.x>>6, lane = threadIdx.x&63, q = lane>>4, li = lane&15;
  int m0 = blockIdx.x*64 + wave*16;
  const u16* arow = Hg + (size_t)(m0+li)*64 + q*8;
  bf16x8 a0 = *(const bf16x8*)arow;
  bf16x8 a1 = *(const bf16x8*)(arow + 32);
  for (int nt=0; nt<16; nt++){
    const u16* brow = W1 + (size_t)(nt*16+li)*64 + q*8;
    bf16x8 b0 = *(const bf16x8*)brow;
    bf16x8 b1v = *(const bf16x8*)(brow + 32);
    f32x4 c = {0.f,0.f,0.f,0.f};
    c = mfma16(a0, b0, c);
    c = mfma16(a1, b1v, c);
    int col = nt*16 + li;
    float bv = b1[col];
    #pragma unroll
    for (int r=0;r<4;r++){
      float v = c[r] + bv;
      v = v*0.5f*(1.f + erff(v*0.70710678118f));
      panel[wave][q*4+r][col] = f2b(v);
    }
  }
  bf16x8 ap[8];
  #pragma unroll
  for (int kb=0;kb<8;kb++) ap[kb] = *(const bf16x8*)&panel[wave][li][kb*32 + q*8];
  f32x4 acc[4];
  #pragma unroll
  for (int nd=0;nd<4;nd++) acc[nd] = (f32x4){0.f,0.f,0.f,0.f};
  #pragma unroll
  for (int kb=0; kb<8; kb++){
    #pragma unroll
    for (int nd=0;nd<4;nd++){
      bf16x8 b = *(const bf16x8*)(W2 + (size_t)(nd*16+li)*256 + kb*32 + q*8);
      acc[nd] = mfma16(ap[kb], b, acc[nd]);
    }
  }
  float tv[4][4]; float gv[4], bvn[4];
  #pragma unroll
  for (int nd=0;nd<4;nd++){
    int col = nd*16 + li;
    float bv = b2[col];
    gv[nd] = lng[col]; bvn[nd] = lnb[col];
    #pragma unroll
    for (int r=0;r<4;r++){
      size_t off = (size_t)(m0 + q*4 + r)*64 + col;
      float v = t[off] + acc[nd][r] + bv;
      t[off] = v;
      tv[nd][r] = v;
    }
  }
  #pragma unroll
  for (int r=0;r<4;r++){
    float s = tv[0][r]+tv[1][r]+tv[2][r]+tv[3][r];
    #pragma unroll
    for (int off=8; off; off>>=1) s += __shfl_xor(s, off);
    float mean = s*(1.f/64.f);
    float qs = 0.f;
    #pragma unroll
    for (int nd=0;nd<4;nd++){ float d = tv[nd][r]-mean; qs += d*d; }
    #pragma unroll
    for (int off=8; off; off>>=1) qs += __shfl_xor(qs, off);
    float rinv = rsqrtf(qs*(1.f/64.f) + 1e-5f);
    size_t rowoff = (size_t)(m0 + q*4 + r)*64;
    #pragma unroll
    for (int nd=0;nd<4;nd++){
      int col = nd*16 + li;
      HgOut[rowoff + col] = f2b((tv[nd][r]-mean)*rinv*gv[nd] + bvn[nd]);
    }
  }
}

// ---------------- PrimaryCaps via MFMA + fused squash: one block per sample
__global__ __launch_bounds__(TPB) void pcaps_mfma(const float* __restrict__ t,
    const u16* __restrict__ wpc, const float* __restrict__ bias, float* __restrict__ caps){
  int b = blockIdx.x;
  int wave = threadIdx.x>>6, lane = threadIdx.x&63, q = lane>>4, li = lane&15;
  int mt = wave & 1, nh = wave >> 1;
  const float* tb = t + (size_t)b*180*64;
  int pos_a = mt*16 + li;
  int oy_a = pos_a >> 3, ox_a = pos_a & 7;
  f32x4 acc[8];
  #pragma unroll
  for (int nt=0;nt<8;nt++) acc[nt] = (f32x4){0.f,0.f,0.f,0.f};
  for (int ks=0; ks<18; ks++){
    int k0 = ks*32 + q*8;
    int r9 = k0 >> 6, ic = k0 & 63;
    int dy = r9/3, dx = r9 - 3*dy;
    const float* src = tb + ((2*oy_a+dy)*18 + (2*ox_a+dx))*64 + ic;
    float4 f0 = *(const float4*)src;
    float4 f1 = *(const float4*)(src+4);
    bf16x8 a;
    a[0]=(short)f2b(f0.x); a[1]=(short)f2b(f0.y); a[2]=(short)f2b(f0.z); a[3]=(short)f2b(f0.w);
    a[4]=(short)f2b(f1.x); a[5]=(short)f2b(f1.y); a[6]=(short)f2b(f1.z); a[7]=(short)f2b(f1.w);
    #pragma unroll
    for (int nt=0;nt<8;nt++){
      bf16x8 bb8 = *(const bf16x8*)(wpc + (size_t)(nh*128 + nt*16 + li)*576 + k0);
      acc[nt] = mfma16(a, bb8, acc[nt]);
    }
  }
  #pragma unroll
  for (int nt=0;nt<8;nt++){
    int oc = nh*128 + nt*16 + li;
    float bv = bias[oc];
    #pragma unroll
    for (int r=0;r<4;r++){
      int prow = mt*16 + q*4 + r;
      float val = acc[nt][r] + bv;
      float l2 = val*val;
      l2 += __shfl_xor(l2, 1);
      l2 += __shfl_xor(l2, 2);
      l2 += __shfl_xor(l2, 4);
      float sc = (l2 > 0.f) ? l2/((1.f+l2)*sqrtf(l2)) : 0.f;
      caps[((size_t)b*1024 + (oc>>3)*32 + prow)*8 + (oc&7)] = val*sc;
    }
  }
}

// ---------------- u[b,i,o] = caps[b,i,:] . cwT[i,o,:]
__global__ __launch_bounds__(TPB) void u_kernel(const float* __restrict__ caps,
    const float* __restrict__ cwT, float* __restrict__ u){
  int gid = blockIdx.x*TPB + threadIdx.x;
  int o = gid % 48; int i = (gid/48) & 1023; int b = gid/(48*1024);
  const float* cp = caps + ((size_t)b*1024 + i)*8;
  const float* wp = cwT + ((size_t)i*48 + o)*8;
  float4 c0 = *(const float4*)cp, c1 = *(const float4*)(cp+4);
  float4 w0 = *(const float4*)wp, w1 = *(const float4*)(wp+4);
  u[gid] = c0.x*w0.x + c0.y*w0.y + c0.z*w0.z + c0.w*w0.w
         + c1.x*w1.x + c1.y*w1.y + c1.z*w1.z + c1.w*w1.w;
}

__global__ __launch_bounds__(TPB) void routing_kernel(const float* __restrict__ u,
    const float* __restrict__ b_route, float* __restrict__ out){
  __shared__ float bb[3072];
  __shared__ float vsh[48];
  __shared__ float red[4][48];
  __shared__ float ssh[48];
  int b = blockIdx.x, tid = threadIdx.x;
  const float* ub = u + (size_t)b*49152;
  for (int idx=tid; idx<3072; idx+=TPB) bb[idx] = b_route[idx];
  __syncthreads();
  for (int it=0; it<4; it++){
    if (it > 0){
      for (int idx=tid; idx<3072; idx+=TPB){
        int i = idx/3, j = idx - i*3;
        const float* up = ub + i*48 + j*16;
        float s = 0.f;
        #pragma unroll
        for (int e=0;e<16;e++) s += up[e]*vsh[j*16+e];
        bb[idx] += s;
      }
      __syncthreads();
    }
    float acc[48];
    #pragma unroll
    for (int q2=0;q2<48;q2++) acc[q2] = 0.f;
    for (int i=tid; i<1024; i+=TPB){
      float b0=bb[i*3], b1=bb[i*3+1], b2v=bb[i*3+2];
      float m = fmaxf(b0, fmaxf(b1, b2v));
      float e0=__expf(b0-m), e1=__expf(b1-m), e2=__expf(b2v-m);
      float inv = 1.f/(e0+e1+e2);
      float c0=e0*inv, c1=e1*inv, c2=e2*inv;
      const float* up = ub + i*48;
      #pragma unroll
      for (int e=0;e<16;e++){
        acc[e]    += c0*up[e];
        acc[16+e] += c1*up[16+e];
        acc[32+e] += c2*up[32+e];
      }
    }
    #pragma unroll
    for (int q2=0;q2<48;q2++){
      float v = acc[q2];
      #pragma unroll
      for (int off=32; off; off>>=1) v += __shfl_xor(v, off);
      if ((tid&63)==0) red[tid>>6][q2] = v;
    }
    __syncthreads();
    if (tid < 48) ssh[tid] = red[0][tid]+red[1][tid]+red[2][tid]+red[3][tid];
    __syncthreads();
    if (tid < 48){
      int j = tid >> 4;
      float l2 = 0.f;
      #pragma unroll
      for (int e=0;e<16;e++) l2 += ssh[j*16+e]*ssh[j*16+e];
      float sc = (l2 > 0.f) ? l2/((1.f+l2)*sqrtf(l2)) : 0.f;
      vsh[tid] = ssh[tid]*sc;
    }
    __syncthreads();
  }
  if (tid < 3){
    float l2 = 0.f;
    #pragma unroll
    for (int e=0;e<16;e++) l2 += vsh[tid*16+e]*vsh[tid*16+e];
    out[b*3+tid] = sqrtf(l2);
  }
}

extern "C" void kernel_launch(void* const* d_in, const int* in_sizes, int n_in,
                              void* d_out, int out_size, void* d_ws, size_t ws_size,
                              hipStream_t stream){
  const float* x       = (const float*)d_in[0];
  const float* conv1_w = (const float*)d_in[1];
  const float* conv2_w = (const float*)d_in[2];
  const float* pos_emb = (const float*)d_in[3];
  const float* ln1_g   = (const float*)d_in[4];
  const float* ln1_b   = (const float*)d_in[5];
  const float* qkv_w   = (const float*)d_in[6];
  const float* out_w   = (const float*)d_in[7];
  const float* out_b   = (const float*)d_in[8];
  const float* ln2_g   = (const float*)d_in[9];
  const float* ln2_b   = (const float*)d_in[10];
  const float* ff1_w   = (const float*)d_in[11];
  const float* ff1_b   = (const float*)d_in[12];
  const float* ff2_w   = (const float*)d_in[13];
  const float* ff2_b   = (const float*)d_in[14];
  const float* pc_w    = (const float*)d_in[15];
  const float* pc_b    = (const float*)d_in[16];
  const float* caps_w  = (const float*)d_in[17];
  const float* b_route = (const float*)d_in[18];
  float* out = (float*)d_out;

  // ---- workspace: peak 95,920,128 B (< 97.3 MB proven safe) ----
  char* ws = (char*)d_ws;
  float* t_buf = (float*)(ws);                  // [46080,64] f32   0 .. 11,796,480
  u16*  Hg    = (u16*)(ws + 11796480);          // [46080,64] bf16  .. 17,694,720
  u16*  WQKVT = (u16*)(ws + 17694720);          // [12][2304][64]   .. 21,233,664
  u16*  WOT   = (u16*)(ws + 21233664);          // [12][64][768]    .. 22,413,312
  u16*  WF1T  = (u16*)(ws + 22413312);          // [12][256][64]    .. 22,806,528
  u16*  WF2T  = (u16*)(ws + 22806528);          // [12][64][256]    .. 23,199,744
  u16*  wpc   = (u16*)(ws + 23199744);          // [256][576] bf16  .. 23,494,656
  float* cwT  = (float*)(ws + 23494656);        // [1024][48][8]    .. 25,067,520
  u16*  wc2   = (u16*)(ws + 25067520);          // [64][576] bf16   .. 25,141,248
  char* win   = ws + 25141248;                  // 70,778,880 B window .. 95,920,128
  u16*  Og    = (u16*)win;                      // [46080][768] bf16 (transformer)
  u16*  p1out = (u16*)win;                      // [256][720][64] bf16 23,592,960
  u16*  c1out = (u16*)(win + 23592960);         // [64][2880][64] bf16 chunk 23,592,960
  float* c2out = (float*)(win + 23592960);      // [256][720][64] f32 47,185,920 (c1out dead)
  float* caps  = (float*)(win);                 //  8,388,608 (tail)
  float* u_buf = (float*)(win + 8388608);       // 50,331,648 (tail)

  // ---- weight prep ----
  tcvt_kernel<<<6912, TPB, 0, stream>>>(qkv_w, WQKVT, 64, 2304, 12*64*2304);
  tcvt_kernel<<<2304, TPB, 0, stream>>>(out_w, WOT, 768, 64, 12*768*64);
  tcvt_kernel<<<768, TPB, 0, stream>>>(ff1_w, WF1T, 64, 256, 12*64*256);
  tcvt_kernel<<<768, TPB, 0, stream>>>(ff2_w, WF2T, 256, 64, 12*256*64);
  tcvt_conv<<<576, TPB, 0, stream>>>(pc_w, wpc, 147456);
  tcvt_conv<<<144, TPB, 0, stream>>>(conv2_w, wc2, 36864);
  tcvt_cw<<<1536, TPB, 0, stream>>>(caps_w, cwT);

  // ---- conv-embed: conv1+pool1 per 64-sample chunk (NHWC bf16), then full-batch conv2 ----
  for (int c = 0; c < 4; c++){
    conv1_kernel<<<46080, TPB, 0, stream>>>(x + (size_t)c*64*3*2880, conv1_w, c1out);
    maxpool1_kernel<<<2880, TPB, 0, stream>>>(c1out, p1out + (size_t)c*64*720*64);
  }
  conv2_mfma<<<dim3(12,256), TPB, 0, stream>>>(p1out, wc2, c2out);
  pool2pos_kernel<<<2880, TPB, 0, stream>>>(c2out, pos_emb, t_buf);

  // ---- transformer: initial LN1, then 24 x {attn, outp(+LN2), ffn(+LN1-next)} ----
  ln_kernel<<<11520, TPB, 0, stream>>>(t_buf, ln1_g, ln1_b, Hg);
  for (int itr=0; itr<24; itr++){
    int l = itr % 12;
    int ln = (itr+1) % 12;
    attn_fused<<<dim3(12,256), TPB, 0, stream>>>(Hg, WQKVT + (size_t)l*2304*64, Og);
    gemm_outp<<<720, TPB, 0, stream>>>(Og, WOT + (size_t)l*64*768, out_b + l*64,
                                       ln2_g + l*64, ln2_b + l*64, t_buf, Hg);
    gemm_ffn<<<720, TPB, 0, stream>>>(Hg, WF1T + (size_t)l*256*64, ff1_b + l*256,
                                      WF2T + (size_t)l*64*256, ff2_b + l*64,
                                      ln1_g + ln*64, ln1_b + ln*64, t_buf, Hg);
  }

  // ---- capsule head ----
  pcaps_mfma<<<256, TPB, 0, stream>>>(t_buf, wpc, pc_b, caps);
  u_kernel<<<49152, TPB, 0, stream>>>(caps, cwT, u_buf);
  routing_kernel<<<256, TPB, 0, stream>>>(u_buf, b_route, out);
}